// Round 3
// baseline (251.391 us; speedup 1.0000x reference)
//
#include <hip/hip_runtime.h>
#include <cstdint>

typedef __attribute__((ext_vector_type(8))) short bf16x8;
typedef __attribute__((ext_vector_type(4))) float f32x4;

#define B_   4
#define C_   128
#define H_   128
#define W_   128
#define HP_  130
#define WP_  130
#define O_   256
#define HW_  (H_*W_)          // 16384

// ws layout (byte offsets)
#define XPAD_BYTES   (B_*HP_*WP_*C_*2)          // bf16 xpad: 17,305,600
#define OFF_BYTE     XPAD_BYTES
#define OFF_BYTES    (B_*HW_*18*4)              // 4,718,592
#define WREPB_BYTE   (OFF_BYTE + OFF_BYTES)
#define WREPB_BYTES  (9*C_*O_*2)                // 589,824
#define STATS_BYTE   (WREPB_BYTE + WREPB_BYTES)
#define WOFF_BYTE    (STATS_BYTE + 4096)
#define WOFF_BYTES   (9*4*4*32*8*2)             // 73,728

typedef __attribute__((address_space(1))) const void gconst_void;
typedef __attribute__((address_space(3))) void lds_void;
#define GLD_LDS16(gp, lp) __builtin_amdgcn_global_load_lds((gconst_void*)(gp), (lds_void*)(lp), 16, 0, 0)

__device__ __forceinline__ unsigned pack_bf2(float a, float b) {
    unsigned ua = __builtin_bit_cast(unsigned, a) + 0x8000u;
    unsigned ub = __builtin_bit_cast(unsigned, b) + 0x8000u;
    return __builtin_amdgcn_perm(ub, ua, 0x07060302u);
}

// ---------------- K1: NCHW fp32 -> padded NHWC bf16 transpose ----------------
__global__ void k_transpose(const float* __restrict__ x, unsigned short* __restrict__ xpad) {
    __shared__ float tile[32][33];   // [c_loc][w_loc]
    int w0 = blockIdx.x * 32, c0 = blockIdx.y * 32;
    int bh = blockIdx.z;
    int b = bh >> 7, h = bh & 127;
    int tx = threadIdx.x, ty = threadIdx.y;
#pragma unroll
    for (int i = 0; i < 4; i++) {
        int c = c0 + ty + i * 8;
        tile[ty + i * 8][tx] = x[((b * C_ + c) * H_ + h) * W_ + w0 + tx];
    }
    __syncthreads();
    int tid = ty * 32 + tx;
    int cp = tid & 15;
    int wl = tid >> 4;
#pragma unroll
    for (int i = 0; i < 2; i++) {
        int wll = wl + i * 16;
        int w = w0 + wll;
        unsigned v = pack_bf2(tile[2 * cp][wll], tile[2 * cp + 1][wll]);
        *(unsigned*)(&xpad[((size_t)((b * HP_ + h + 1) * WP_ + (w + 1))) * C_ + c0 + 2 * cp]) = v;
    }
}

// ---------------- K2a: repack p_w -> bf16 A-fragments [tap][kc][q][m32][e8], m>=18 zero ----------------
__global__ void k_repack2(const float* __restrict__ p_w, short* __restrict__ wofff) {
    int i = blockIdx.x * 256 + threadIdx.x;
    if (i < 9 * 4096) {
        int e = i & 7, m = (i >> 3) & 31, q = (i >> 8) & 3, kc = (i >> 10) & 3, tap = i >> 12;
        float f = (m < 18) ? p_w[((size_t)m * C_ + kc * 32 + q * 8 + e) * 9 + tap] : 0.f;
        unsigned u = __builtin_bit_cast(unsigned, f);
        u += 0x7fffu + ((u >> 16) & 1u);   // RNE
        wofff[i] = (short)(u >> 16);
    }
}

// ---------------- K2: offset conv as MFMA GEMM (M=18 pad 32, K=1152) ----------------
__global__ __launch_bounds__(256) void k_offconv(const unsigned short* __restrict__ xpad,
                                                 const short* __restrict__ wofff,
                                                 const float* __restrict__ p_b,
                                                 float* __restrict__ offT) {
    int t = threadIdx.x;
    int ph = blockIdx.x;
    int h  = blockIdx.y;
    int b  = blockIdx.z;
    const unsigned short* xb = xpad + (size_t)b * HP_ * WP_ * C_;
    int lane = t & 63, wv = t >> 6;
    int q = lane >> 4, l15 = lane & 15;
    int pos0 = ph * 64 + wv * 16;
    int poscol = pos0 + l15;

    f32x4 accA = {0.f, 0.f, 0.f, 0.f}, accB = {0.f, 0.f, 0.f, 0.f};
    const bf16x8* Wf = (const bf16x8*)wofff;

    for (int tap = 0; tap < 9; tap++) {
        int row = h + tap / 3;
        int col = poscol + tap % 3;
        const unsigned short* src = xb + ((size_t)(row * WP_ + col)) * C_ + q * 8;
#pragma unroll
        for (int kc = 0; kc < 4; kc++) {
            bf16x8 a0 = Wf[(size_t)(((tap * 4 + kc) * 4 + q) * 32) + l15];
            bf16x8 a1 = Wf[(size_t)(((tap * 4 + kc) * 4 + q) * 32) + 16 + l15];
            bf16x8 bv = *(const bf16x8*)(src + kc * 32);
            accA = __builtin_amdgcn_mfma_f32_16x16x32_bf16(a0, bv, accA, 0, 0, 0);
            accB = __builtin_amdgcn_mfma_f32_16x16x32_bf16(a1, bv, accB, 0, 0, 0);
        }
    }
    size_t hw = (size_t)h * W_ + pos0 + l15;
#pragma unroll
    for (int r = 0; r < 4; r++) {
        int j = q * 4 + r;
        offT[((size_t)(b * 18 + j)) * HW_ + hw] = accA[r] + p_b[j];
    }
    if (q == 0) {
#pragma unroll
        for (int r = 0; r < 2; r++) {
            int j = 16 + r;
            offT[((size_t)(b * 18 + j)) * HW_ + hw] = accB[r] + p_b[j];
        }
    }
}

// ---------------- K2b: repack w_conv -> bf16 [n][kc4][kq4][o256][ki8] ----------------
__global__ void k_repack(const float* __restrict__ w_conv, unsigned short* __restrict__ wrepb) {
    int i = blockIdx.x * 256 + threadIdx.x;
    if (i < 9 * C_ * O_) {
        int ki8 = i & 7;
        int o   = (i >> 3) & 255;
        int kq  = (i >> 11) & 3;
        int kc  = (i >> 13) & 3;
        int n   = i >> 15;
        int c = kc * 32 + kq * 8 + ki8;
        float f = w_conv[(o * C_ + c) * 9 + n];
        unsigned u = __builtin_bit_cast(unsigned, f);
        u += 0x7fffu + ((u >> 16) & 1u);   // RNE
        wrepb[i] = (unsigned short)(u >> 16);
    }
}

// ---------------- K3: one block per (b,h); 2-step gather lookahead + counted-vmcnt raw barriers ----------------
__global__ __launch_bounds__(512, 4) void k_main(const unsigned short* __restrict__ xpad,
                                                 const float* __restrict__ offT,
                                                 const unsigned short* __restrict__ wrepb,
                                                 float* __restrict__ out,
                                                 float* __restrict__ stats) {
    __shared__ short Wl[2][8192];        // double-buffered W chunk, 32 KB
    __shared__ short Vl[2][4128];        // double-buffered skewed V, 16.1 KB
    __shared__ int   pbase[2][4][128];   // tap-parity double buffer, 4 KB
    __shared__ float pg[2][4][128];      // 4 KB
    __shared__ float red0[256], red1[256];

    int t = threadIdx.x;
    int i_blk = blockIdx.x;
    int b = i_blk & 3;                   // XCD k serves b = k&3 only (round-robin heuristic)
    int h = i_blk >> 2;
    const unsigned short* xb = xpad + (size_t)b * HP_ * WP_ * C_;

    int lane = t & 63, wv = t >> 6;      // 8 waves
    int q = lane >> 4, l15 = lane & 15;
    int m0 = (wv & 3) * 64;              // o-slice
    int ph = wv >> 2;                    // pos half
    int n0 = ph * 64;
    int c4g = t & 3, posb = t >> 2;      // gather: 4 ch-subquads x 128 pos

    auto OFFSETS = [&](int n, int pb) {
        if (t < 128) {
            int w = t;
            float offx = offT[((size_t)(b * 18 + n)) * HW_ + h * W_ + w];
            float offy = offT[((size_t)(b * 18 + 9 + n)) * HW_ + h * W_ + w];
            int dxn = n / 3 - 1, dyn = n % 3 - 1;
            float px = (float)(h + 1 + dxn) + offx;
            float py = (float)(w + 1 + dyn) + offy;
            float pcx = fminf(fmaxf(px, 0.f), 129.f);
            float pcy = fminf(fmaxf(py, 0.f), 129.f);
            float fx = floorf(px), fy = floorf(py);
            float q0x = fminf(fmaxf(fx, 0.f), 129.f);
            float q0y = fminf(fmaxf(fy, 0.f), 129.f);
            float q1x = fminf(fmaxf(fx + 1.f, 0.f), 129.f);
            float q1y = fminf(fmaxf(fy + 1.f, 0.f), 129.f);
            float wx0 = 1.f + (q0x - pcx), wx1 = 1.f - (q1x - pcx);
            float wy0 = 1.f + (q0y - pcy), wy1 = 1.f - (q1y - pcy);
            int i0x = (int)q0x, i0y = (int)q0y, i1x = (int)q1x, i1y = (int)q1y;
            pbase[pb][0][w] = (i0x * WP_ + i0y) * C_;
            pbase[pb][1][w] = (i1x * WP_ + i1y) * C_;
            pbase[pb][2][w] = (i0x * WP_ + i1y) * C_;
            pbase[pb][3][w] = (i1x * WP_ + i0y) * C_;
            pg[pb][0][w] = wx0 * wy0;
            pg[pb][1][w] = wx1 * wy1;
            pg[pb][2][w] = wx0 * wy1;
            pg[pb][3][w] = wx1 * wy0;
        }
    };

    struct GSet { uint4 A, B, C, D; };
    GSet ga, gb;

    auto GISSUE = [&](GSet& g, int s2) {
        int pb = (s2 >> 2) & 1;
        int cof = (s2 & 3) * 32 + c4g * 8;
        g.A = *(const uint4*)(xb + pbase[pb][0][posb] + cof);
        g.B = *(const uint4*)(xb + pbase[pb][1][posb] + cof);
        g.C = *(const uint4*)(xb + pbase[pb][2][posb] + cof);
        g.D = *(const uint4*)(xb + pbase[pb][3][posb] + cof);
    };

    auto BLEND = [&](GSet& g, int sb, int buf) {
        int pb = (sb >> 2) & 1;
        float g0 = pg[pb][0][posb], g1 = pg[pb][1][posb];
        float g2 = pg[pb][2][posb], g3 = pg[pb][3][posb];
        unsigned outw[4];
#pragma unroll
        for (int k = 0; k < 4; k++) {
            unsigned ua = (&g.A.x)[k], ub = (&g.B.x)[k], uc = (&g.C.x)[k], ud = (&g.D.x)[k];
            float alo = __builtin_bit_cast(float, ua << 16), ahi = __builtin_bit_cast(float, ua & 0xffff0000u);
            float blo = __builtin_bit_cast(float, ub << 16), bhi = __builtin_bit_cast(float, ub & 0xffff0000u);
            float clo = __builtin_bit_cast(float, uc << 16), chi = __builtin_bit_cast(float, uc & 0xffff0000u);
            float dlo = __builtin_bit_cast(float, ud << 16), dhi = __builtin_bit_cast(float, ud & 0xffff0000u);
            float vlo = g0 * alo + g1 * blo + g2 * clo + g3 * dlo;
            float vhi = g0 * ahi + g1 * bhi + g2 * chi + g3 * dhi;
            outw[k] = pack_bf2(vlo, vhi);
        }
        *(uint4*)&Vl[buf][(unsigned)(c4g * 129 + posb) * 8] = make_uint4(outw[0], outw[1], outw[2], outw[3]);
    };

    f32x4 acc[4][4];
#pragma unroll
    for (int i = 0; i < 4; i++)
#pragma unroll
        for (int j = 0; j < 4; j++) acc[i][j] = (f32x4){0.f, 0.f, 0.f, 0.f};

    OFFSETS(0, 0);
    __syncthreads();

    // ---- prologue: stage step 0, pre-issue gathers for steps 0 and 1 ----
    {
        const unsigned short* ws = wrepb;            // chunk 0
        GLD_LDS16(ws + (size_t)t * 8, &Wl[0][wv * 512]);
        GLD_LDS16(ws + (size_t)(t + 512) * 8, &Wl[0][wv * 512 + 4096]);
        GISSUE(ga, 0);
        BLEND(ga, 0, 0);        // Vl[0] for step 0 (latency exposed once)
        GISSUE(ga, 1);          // pending for step 1
    }
    __syncthreads();            // full drain once at prologue end

    // ---- step s: stage W(s+1) [VMEM first], issue gathers(s+2), MFMA(s), blend(s+1),
    //      fence {vmcnt(4) keeps s+2 gathers in flight across the barrier} ----
    auto STEP = [&](GSet& pend, GSet& fill, int s, int vm) {
        int cur = s & 1, nxt = cur ^ 1;
        if (s <= 34) {
            const unsigned short* ws = wrepb + (size_t)(s + 1) * 8192;
            GLD_LDS16(ws + (size_t)t * 8, &Wl[nxt][wv * 512]);
            GLD_LDS16(ws + (size_t)(t + 512) * 8, &Wl[nxt][wv * 512 + 4096]);
        }
        __builtin_amdgcn_sched_barrier(0);   // pin: gld_lds issued before gathers (vmcnt order)
        if (s <= 33) GISSUE(fill, s + 2);
        {
            const bf16x8* Af = (const bf16x8*)Wl[cur];
            const bf16x8* Bf = (const bf16x8*)Vl[cur];
            bf16x8 av[4];
#pragma unroll
            for (int i = 0; i < 4; i++) av[i] = Af[q * 256 + m0 + i * 16 + l15];
            __builtin_amdgcn_s_setprio(1);
#pragma unroll
            for (int j = 0; j < 4; j++) {
                bf16x8 bv = Bf[q * 129 + n0 + j * 16 + l15];
#pragma unroll
                for (int i = 0; i < 4; i++)
                    acc[i][j] = __builtin_amdgcn_mfma_f32_16x16x32_bf16(av[i], bv, acc[i][j], 0, 0, 0);
            }
            __builtin_amdgcn_s_setprio(0);
        }
        if ((s & 3) == 1) {
            int n1 = (s >> 2) + 1;
            if (n1 <= 8) OFFSETS(n1, n1 & 1);
        }
        if (s <= 34) BLEND(pend, s + 1, nxt);
        __builtin_amdgcn_sched_barrier(0);
        if (vm == 4) asm volatile("s_waitcnt vmcnt(4) lgkmcnt(0)" ::: "memory");
        else         asm volatile("s_waitcnt vmcnt(0) lgkmcnt(0)" ::: "memory");
        __builtin_amdgcn_s_barrier();
        __builtin_amdgcn_sched_barrier(0);
    };

    for (int s = 0; s < 34; s += 2) {
        STEP(ga, gb, s, 4);
        STEP(gb, ga, s + 1, 4);
    }
    STEP(ga, gb, 34, 0);   // no new gathers -> full drain so Wl/Vl for 35 are ready
    STEP(gb, ga, 35, 0);

    // ---- epilogue: BN partial sums ----
    if (t < 256) { red0[t] = 0.f; red1[t] = 0.f; }
    __syncthreads();
#pragma unroll
    for (int i = 0; i < 4; i++) {
#pragma unroll
        for (int r = 0; r < 4; r++) {
            int o_loc = m0 + i * 16 + q * 4 + r;
            float s = 0.f, s2 = 0.f;
#pragma unroll
            for (int j = 0; j < 4; j++) { float v = acc[i][j][r]; s += v; s2 += v * v; }
            s  += __shfl_xor(s, 1);  s  += __shfl_xor(s, 2);  s  += __shfl_xor(s, 4);  s  += __shfl_xor(s, 8);
            s2 += __shfl_xor(s2, 1); s2 += __shfl_xor(s2, 2); s2 += __shfl_xor(s2, 4); s2 += __shfl_xor(s2, 8);
            if (l15 == 0) { atomicAdd(&red0[o_loc], s); atomicAdd(&red1[o_loc], s2); }
        }
    }
    __syncthreads();
    if (t < 256) {
        atomicAdd(&stats[t], red0[t]);
        atomicAdd(&stats[256 + t], red1[t]);
    }

    // ---- epilogue: direct C write (64B segments per 16-lane group; L2 write-combines) ----
    float* outb = out + ((size_t)b * O_) * HW_ + (size_t)h * W_;
#pragma unroll
    for (int i = 0; i < 4; i++)
#pragma unroll
        for (int j = 0; j < 4; j++) {
            int col = ph * 64 + j * 16 + l15;
#pragma unroll
            for (int r = 0; r < 4; r++) {
                int o = m0 + i * 16 + q * 4 + r;
                outb[(size_t)o * HW_ + col] = acc[i][j][r];
            }
        }
}

// ---------------- K4: BN stats finalize ----------------
__global__ void k_bnstats(float* __restrict__ stats,
                          const float* __restrict__ gamma,
                          const float* __restrict__ beta) {
    int t = threadIdx.x;  // 256
    float s = stats[t], s2 = stats[256 + t];
    float mean = s * (1.f / 65536.f);
    float var = s2 * (1.f / 65536.f) - mean * mean;
    float sc = gamma[t] * rsqrtf(var + 1e-5f);
    float sh = beta[t] - mean * sc;
    stats[512 + t] = sc;
    stats[768 + t] = sh;
}

// ---------------- K5: normalize + leaky ReLU (in-place on d_out) ----------------
__global__ __launch_bounds__(256) void k_apply(float* __restrict__ out,
                                               const float* __restrict__ stats) {
    int idx = blockIdx.x * 256 + threadIdx.x;
    int e = idx * 4;
    int o = (e >> 14) & 255;
    float sc = stats[512 + o], sh = stats[768 + o];
    float4 v = *(float4*)(out + e);
    v.x = v.x * sc + sh; v.x = (v.x >= 0.f) ? v.x : 0.1f * v.x;
    v.y = v.y * sc + sh; v.y = (v.y >= 0.f) ? v.y : 0.1f * v.y;
    v.z = v.z * sc + sh; v.z = (v.z >= 0.f) ? v.z : 0.1f * v.z;
    v.w = v.w * sc + sh; v.w = (v.w >= 0.f) ? v.w : 0.1f * v.w;
    *(float4*)(out + e) = v;
}

extern "C" void kernel_launch(void* const* d_in, const int* in_sizes, int n_in,
                              void* d_out, int out_size, void* d_ws, size_t ws_size,
                              hipStream_t stream) {
    const float* x      = (const float*)d_in[0];
    const float* p_w    = (const float*)d_in[1];
    const float* p_b    = (const float*)d_in[2];
    const float* w_conv = (const float*)d_in[3];
    const float* gamma  = (const float*)d_in[4];
    const float* beta   = (const float*)d_in[5];
    float* out = (float*)d_out;

    char* wsb = (char*)d_ws;
    unsigned short* xpad  = (unsigned short*)wsb;
    float*          offT  = (float*)(wsb + OFF_BYTE);
    unsigned short* wrepb = (unsigned short*)(wsb + WREPB_BYTE);
    float*          stats = (float*)(wsb + STATS_BYTE);
    short*          wofff = (short*)(wsb + WOFF_BYTE);

    hipMemsetAsync(xpad, 0, (size_t)XPAD_BYTES, stream);
    hipMemsetAsync(stats, 0, 4096, stream);

    k_transpose<<<dim3(W_ / 32, C_ / 32, B_ * H_), dim3(32, 8), 0, stream>>>(x, xpad);
    k_repack2<<<dim3(144), 256, 0, stream>>>(p_w, wofff);
    k_offconv<<<dim3(2, H_, B_), 256, 0, stream>>>(xpad, wofff, p_b, offT);
    k_repack<<<dim3((9 * C_ * O_ + 255) / 256), 256, 0, stream>>>(w_conv, wrepb);
    k_main<<<dim3(512), 512, 0, stream>>>(xpad, offT, wrepb, out, stats);
    k_bnstats<<<1, 256, 0, stream>>>(stats, gamma, beta);
    k_apply<<<dim3(16384), 256, 0, stream>>>(out, stats);
}

// Round 4
// 251.218 us; speedup vs baseline: 1.0007x; 1.0007x over previous
//
#include <hip/hip_runtime.h>
#include <cstdint>

typedef __attribute__((ext_vector_type(8))) short bf16x8;
typedef __attribute__((ext_vector_type(4))) float f32x4;

#define B_   4
#define C_   128
#define H_   128
#define W_   128
#define HP_  130
#define WP_  130
#define O_   256
#define HW_  (H_*W_)          // 16384

// ws layout (byte offsets)
#define XPAD_BYTES   (B_*HP_*WP_*C_*2)          // bf16 xpad: 17,305,600
#define OFF_BYTE     XPAD_BYTES
#define OFF_BYTES    (B_*HW_*18*4)              // 4,718,592
#define WREPB_BYTE   (OFF_BYTE + OFF_BYTES)
#define WREPB_BYTES  (9*C_*O_*2)                // 589,824
#define STATS_BYTE   (WREPB_BYTE + WREPB_BYTES)
#define WOFF_BYTE    (STATS_BYTE + 4096)
#define WOFF_BYTES   (9*4*4*32*8*2)             // 73,728

typedef __attribute__((address_space(1))) const void gconst_void;
typedef __attribute__((address_space(3))) void lds_void;
#define GLD_LDS16(gp, lp) __builtin_amdgcn_global_load_lds((gconst_void*)(gp), (lds_void*)(lp), 16, 0, 0)

__device__ __forceinline__ unsigned pack_bf2(float a, float b) {
    unsigned ua = __builtin_bit_cast(unsigned, a) + 0x8000u;
    unsigned ub = __builtin_bit_cast(unsigned, b) + 0x8000u;
    return __builtin_amdgcn_perm(ub, ua, 0x07060302u);
}

// ---------------- K1: NCHW fp32 -> padded NHWC bf16 transpose ----------------
__global__ void k_transpose(const float* __restrict__ x, unsigned short* __restrict__ xpad) {
    __shared__ float tile[32][33];   // [c_loc][w_loc]
    int w0 = blockIdx.x * 32, c0 = blockIdx.y * 32;
    int bh = blockIdx.z;
    int b = bh >> 7, h = bh & 127;
    int tx = threadIdx.x, ty = threadIdx.y;
#pragma unroll
    for (int i = 0; i < 4; i++) {
        int c = c0 + ty + i * 8;
        tile[ty + i * 8][tx] = x[((b * C_ + c) * H_ + h) * W_ + w0 + tx];
    }
    __syncthreads();
    int tid = ty * 32 + tx;
    int cp = tid & 15;
    int wl = tid >> 4;
#pragma unroll
    for (int i = 0; i < 2; i++) {
        int wll = wl + i * 16;
        int w = w0 + wll;
        unsigned v = pack_bf2(tile[2 * cp][wll], tile[2 * cp + 1][wll]);
        *(unsigned*)(&xpad[((size_t)((b * HP_ + h + 1) * WP_ + (w + 1))) * C_ + c0 + 2 * cp]) = v;
    }
}

// ---------------- K2ab fused: repack p_w -> wofff AND w_conv -> wrepb ----------------
__global__ void k_repackA(const float* __restrict__ p_w, short* __restrict__ wofff,
                          const float* __restrict__ w_conv, unsigned short* __restrict__ wrepb) {
    int i = blockIdx.x * 256 + threadIdx.x;
    if (i < 9 * 4096) {
        int e = i & 7, m = (i >> 3) & 31, q = (i >> 8) & 3, kc = (i >> 10) & 3, tap = i >> 12;
        float f = (m < 18) ? p_w[((size_t)m * C_ + kc * 32 + q * 8 + e) * 9 + tap] : 0.f;
        unsigned u = __builtin_bit_cast(unsigned, f);
        u += 0x7fffu + ((u >> 16) & 1u);   // RNE
        wofff[i] = (short)(u >> 16);
    }
    int j = i - 9 * 4096;
    if (j >= 0 && j < 9 * C_ * O_) {
        int ki8 = j & 7;
        int o   = (j >> 3) & 255;
        int kq  = (j >> 11) & 3;
        int kc  = (j >> 13) & 3;
        int n   = j >> 15;
        int c = kc * 32 + kq * 8 + ki8;
        float f = w_conv[(o * C_ + c) * 9 + n];
        unsigned u = __builtin_bit_cast(unsigned, f);
        u += 0x7fffu + ((u >> 16) & 1u);   // RNE
        wrepb[j] = (unsigned short)(u >> 16);
    }
}

// ---------------- K2: offset conv as MFMA GEMM (M=18 pad 32, K=1152) ----------------
__global__ __launch_bounds__(256) void k_offconv(const unsigned short* __restrict__ xpad,
                                                 const short* __restrict__ wofff,
                                                 const float* __restrict__ p_b,
                                                 float* __restrict__ offT) {
    int t = threadIdx.x;
    int ph = blockIdx.x;
    int h  = blockIdx.y;
    int b  = blockIdx.z;
    const unsigned short* xb = xpad + (size_t)b * HP_ * WP_ * C_;
    int lane = t & 63, wv = t >> 6;
    int q = lane >> 4, l15 = lane & 15;
    int pos0 = ph * 64 + wv * 16;
    int poscol = pos0 + l15;

    f32x4 accA = {0.f, 0.f, 0.f, 0.f}, accB = {0.f, 0.f, 0.f, 0.f};
    const bf16x8* Wf = (const bf16x8*)wofff;

    for (int tap = 0; tap < 9; tap++) {
        int row = h + tap / 3;
        int col = poscol + tap % 3;
        const unsigned short* src = xb + ((size_t)(row * WP_ + col)) * C_ + q * 8;
#pragma unroll
        for (int kc = 0; kc < 4; kc++) {
            bf16x8 a0 = Wf[(size_t)(((tap * 4 + kc) * 4 + q) * 32) + l15];
            bf16x8 a1 = Wf[(size_t)(((tap * 4 + kc) * 4 + q) * 32) + 16 + l15];
            bf16x8 bv = *(const bf16x8*)(src + kc * 32);
            accA = __builtin_amdgcn_mfma_f32_16x16x32_bf16(a0, bv, accA, 0, 0, 0);
            accB = __builtin_amdgcn_mfma_f32_16x16x32_bf16(a1, bv, accB, 0, 0, 0);
        }
    }
    size_t hw = (size_t)h * W_ + pos0 + l15;
#pragma unroll
    for (int r = 0; r < 4; r++) {
        int j = q * 4 + r;
        offT[((size_t)(b * 18 + j)) * HW_ + hw] = accA[r] + p_b[j];
    }
    if (q == 0) {
#pragma unroll
        for (int r = 0; r < 2; r++) {
            int j = 16 + r;
            offT[((size_t)(b * 18 + j)) * HW_ + hw] = accB[r] + p_b[j];
        }
    }
}

// ---------------- K3: one block per (b,h); R1 pipeline + persistent-block fused BN epilogue ----------------
__global__ __launch_bounds__(512, 4) void k_main(const unsigned short* __restrict__ xpad,
                                                 const float* __restrict__ offT,
                                                 const unsigned short* __restrict__ wrepb,
                                                 float* __restrict__ out,
                                                 float* __restrict__ stats,
                                                 const float* __restrict__ gamma,
                                                 const float* __restrict__ beta) {
    __shared__ short Wl[2][8192];        // double-buffered W chunk, 32 KB
    __shared__ short Vl[2][4128];        // double-buffered skewed V, 16.1 KB
    __shared__ int   pbase[2][4][128];   // tap-parity double buffer, 4 KB
    __shared__ float pg[2][4][128];      // 4 KB
    __shared__ float red0[256], red1[256];

    int t = threadIdx.x;
    int i_blk = blockIdx.x;
    int b = i_blk & 3;                   // XCD k serves b = k&3 only (round-robin heuristic)
    int h = i_blk >> 2;
    const unsigned short* xb = xpad + (size_t)b * HP_ * WP_ * C_;

    int lane = t & 63, wv = t >> 6;      // 8 waves
    int q = lane >> 4, l15 = lane & 15;
    int m0 = (wv & 3) * 64;              // o-slice
    int ph = wv >> 2;                    // pos half
    int n0 = ph * 64;
    int c4g = t & 3, posb = t >> 2;      // gather: 4 ch-subquads x 128 pos

    auto OFFSETS = [&](int n, int pb) {
        if (t < 128) {
            int w = t;
            float offx = offT[((size_t)(b * 18 + n)) * HW_ + h * W_ + w];
            float offy = offT[((size_t)(b * 18 + 9 + n)) * HW_ + h * W_ + w];
            int dxn = n / 3 - 1, dyn = n % 3 - 1;
            float px = (float)(h + 1 + dxn) + offx;
            float py = (float)(w + 1 + dyn) + offy;
            float pcx = fminf(fmaxf(px, 0.f), 129.f);
            float pcy = fminf(fmaxf(py, 0.f), 129.f);
            float fx = floorf(px), fy = floorf(py);
            float q0x = fminf(fmaxf(fx, 0.f), 129.f);
            float q0y = fminf(fmaxf(fy, 0.f), 129.f);
            float q1x = fminf(fmaxf(fx + 1.f, 0.f), 129.f);
            float q1y = fminf(fmaxf(fy + 1.f, 0.f), 129.f);
            float wx0 = 1.f + (q0x - pcx), wx1 = 1.f - (q1x - pcx);
            float wy0 = 1.f + (q0y - pcy), wy1 = 1.f - (q1y - pcy);
            int i0x = (int)q0x, i0y = (int)q0y, i1x = (int)q1x, i1y = (int)q1y;
            pbase[pb][0][w] = (i0x * WP_ + i0y) * C_;
            pbase[pb][1][w] = (i1x * WP_ + i1y) * C_;
            pbase[pb][2][w] = (i0x * WP_ + i1y) * C_;
            pbase[pb][3][w] = (i1x * WP_ + i0y) * C_;
            pg[pb][0][w] = wx0 * wy0;
            pg[pb][1][w] = wx1 * wy1;
            pg[pb][2][w] = wx0 * wy1;
            pg[pb][3][w] = wx1 * wy0;
        }
    };

    f32x4 acc[4][4];
#pragma unroll
    for (int i = 0; i < 4; i++)
#pragma unroll
        for (int j = 0; j < 4; j++) acc[i][j] = (f32x4){0.f, 0.f, 0.f, 0.f};

    OFFSETS(0, 0);
    __syncthreads();

    // ---- prologue: stage step 0 into buffer 0 ----
    {
        const unsigned short* ws = wrepb;            // chunk 0
        GLD_LDS16(ws + (size_t)t * 8, &Wl[0][wv * 512]);
        GLD_LDS16(ws + (size_t)(t + 512) * 8, &Wl[0][wv * 512 + 4096]);
        int cof = c4g * 8;                           // kc=0
        uint4 A  = *(const uint4*)(xb + pbase[0][0][posb] + cof);
        uint4 Bv = *(const uint4*)(xb + pbase[0][1][posb] + cof);
        uint4 Cv = *(const uint4*)(xb + pbase[0][2][posb] + cof);
        uint4 Dv = *(const uint4*)(xb + pbase[0][3][posb] + cof);
        float g0 = pg[0][0][posb], g1 = pg[0][1][posb], g2 = pg[0][2][posb], g3 = pg[0][3][posb];
        unsigned outw[4];
#pragma unroll
        for (int k = 0; k < 4; k++) {
            unsigned ua = (&A.x)[k], ub = (&Bv.x)[k], uc = (&Cv.x)[k], ud = (&Dv.x)[k];
            float alo = __builtin_bit_cast(float, ua << 16), ahi = __builtin_bit_cast(float, ua & 0xffff0000u);
            float blo = __builtin_bit_cast(float, ub << 16), bhi = __builtin_bit_cast(float, ub & 0xffff0000u);
            float clo = __builtin_bit_cast(float, uc << 16), chi = __builtin_bit_cast(float, uc & 0xffff0000u);
            float dlo = __builtin_bit_cast(float, ud << 16), dhi = __builtin_bit_cast(float, ud & 0xffff0000u);
            float vlo = g0 * alo + g1 * blo + g2 * clo + g3 * dlo;
            float vhi = g0 * ahi + g1 * bhi + g2 * chi + g3 * dhi;
            outw[k] = pack_bf2(vlo, vhi);
        }
        *(uint4*)&Vl[0][(unsigned)(c4g * 129 + posb) * 8] = make_uint4(outw[0], outw[1], outw[2], outw[3]);
    }
    __syncthreads();

    // ---- main pipelined loop: 36 steps, 1 barrier per step (R1 proven structure) ----
#pragma unroll 1
    for (int s = 0; s < 36; s++) {
        int cur = s & 1, nxt = cur ^ 1;
        uint4 A, Bv, Cv, Dv;
        float g0 = 0.f, g1 = 0.f, g2 = 0.f, g3 = 0.f;
        bool st = (s < 35);
        if (st) {
            int s1 = s + 1;
            const unsigned short* ws = wrepb + (size_t)s1 * 8192;
            GLD_LDS16(ws + (size_t)t * 8, &Wl[nxt][wv * 512]);
            GLD_LDS16(ws + (size_t)(t + 512) * 8, &Wl[nxt][wv * 512 + 4096]);
            int n1 = s1 >> 2, kc1 = s1 & 3, pb1 = n1 & 1;
            int cof = kc1 * 32 + c4g * 8;
            A  = *(const uint4*)(xb + pbase[pb1][0][posb] + cof);
            Bv = *(const uint4*)(xb + pbase[pb1][1][posb] + cof);
            Cv = *(const uint4*)(xb + pbase[pb1][2][posb] + cof);
            Dv = *(const uint4*)(xb + pbase[pb1][3][posb] + cof);
            g0 = pg[pb1][0][posb]; g1 = pg[pb1][1][posb];
            g2 = pg[pb1][2][posb]; g3 = pg[pb1][3][posb];
        }
        // consume step s: loads for s+1 are in flight underneath the MFMAs
        {
            const bf16x8* Af = (const bf16x8*)Wl[cur];
            const bf16x8* Bf = (const bf16x8*)Vl[cur];
            bf16x8 av[4];
#pragma unroll
            for (int i = 0; i < 4; i++) av[i] = Af[q * 256 + m0 + i * 16 + l15];
            __builtin_amdgcn_s_setprio(1);
#pragma unroll
            for (int j = 0; j < 4; j++) {
                bf16x8 bv = Bf[q * 129 + n0 + j * 16 + l15];
#pragma unroll
                for (int i = 0; i < 4; i++)
                    acc[i][j] = __builtin_amdgcn_mfma_f32_16x16x32_bf16(av[i], bv, acc[i][j], 0, 0, 0);
            }
            __builtin_amdgcn_s_setprio(0);
        }
        // compute offsets one tap ahead (off the critical path, disjoint pb buffer)
        if ((s & 3) == 2) {
            int n = s >> 2;
            if (n < 8) OFFSETS(n + 1, (n + 1) & 1);
        }
        if (st) {
            unsigned outw[4];
#pragma unroll
            for (int k = 0; k < 4; k++) {
                unsigned ua = (&A.x)[k], ub = (&Bv.x)[k], uc = (&Cv.x)[k], ud = (&Dv.x)[k];
                float alo = __builtin_bit_cast(float, ua << 16), ahi = __builtin_bit_cast(float, ua & 0xffff0000u);
                float blo = __builtin_bit_cast(float, ub << 16), bhi = __builtin_bit_cast(float, ub & 0xffff0000u);
                float clo = __builtin_bit_cast(float, uc << 16), chi = __builtin_bit_cast(float, uc & 0xffff0000u);
                float dlo = __builtin_bit_cast(float, ud << 16), dhi = __builtin_bit_cast(float, ud & 0xffff0000u);
                float vlo = g0 * alo + g1 * blo + g2 * clo + g3 * dlo;
                float vhi = g0 * ahi + g1 * bhi + g2 * chi + g3 * dhi;
                outw[k] = pack_bf2(vlo, vhi);
            }
            *(uint4*)&Vl[nxt][(unsigned)(c4g * 129 + posb) * 8] = make_uint4(outw[0], outw[1], outw[2], outw[3]);
        }
        __syncthreads();
    }

    // ---- epilogue: BN partial sums ----
    if (t < 256) { red0[t] = 0.f; red1[t] = 0.f; }
    __syncthreads();
#pragma unroll
    for (int i = 0; i < 4; i++) {
#pragma unroll
        for (int r = 0; r < 4; r++) {
            int o_loc = m0 + i * 16 + q * 4 + r;
            float s = 0.f, s2 = 0.f;
#pragma unroll
            for (int j = 0; j < 4; j++) { float v = acc[i][j][r]; s += v; s2 += v * v; }
            s  += __shfl_xor(s, 1);  s  += __shfl_xor(s, 2);  s  += __shfl_xor(s, 4);  s  += __shfl_xor(s, 8);
            s2 += __shfl_xor(s2, 1); s2 += __shfl_xor(s2, 2); s2 += __shfl_xor(s2, 4); s2 += __shfl_xor(s2, 8);
            if (l15 == 0) { atomicAdd(&red0[o_loc], s); atomicAdd(&red1[o_loc], s2); }
        }
    }
    __syncthreads();
    if (t < 256) {
        atomicAdd(&stats[t], red0[t]);
        atomicAdd(&stats[256 + t], red1[t]);
    }
    __syncthreads();

    // ---- persistent-block handshake: all 512 blocks are co-resident (2/CU exactly) ----
    unsigned* cnt = (unsigned*)(stats + 1020);
    if (t == 0) {
        __threadfence();
        __hip_atomic_fetch_add(cnt, 1u, __ATOMIC_RELEASE, __HIP_MEMORY_SCOPE_AGENT);
        while (__hip_atomic_load(cnt, __ATOMIC_ACQUIRE, __HIP_MEMORY_SCOPE_AGENT) < 512u)
            __builtin_amdgcn_s_sleep(8);
    }
    __syncthreads();

    // ---- fused BN finalize ----
    if (t < 256) {
        float s0  = __hip_atomic_load(&stats[t],       __ATOMIC_RELAXED, __HIP_MEMORY_SCOPE_AGENT);
        float s2v = __hip_atomic_load(&stats[256 + t], __ATOMIC_RELAXED, __HIP_MEMORY_SCOPE_AGENT);
        float mean = s0 * (1.f / 65536.f);
        float var = s2v * (1.f / 65536.f) - mean * mean;
        float sc = gamma[t] * rsqrtf(var + 1e-5f);
        red0[t] = sc;
        red1[t] = beta[t] - mean * sc;
    }
    __syncthreads();

    // ---- normalized + leaky ReLU write, straight from accumulators ----
    float* outb = out + ((size_t)b * O_) * HW_ + (size_t)h * W_;
#pragma unroll
    for (int i = 0; i < 4; i++)
#pragma unroll
        for (int r = 0; r < 4; r++) {
            int o = m0 + i * 16 + q * 4 + r;
            float sc = red0[o], sh = red1[o];
#pragma unroll
            for (int j = 0; j < 4; j++) {
                int col = ph * 64 + j * 16 + l15;
                float v = acc[i][j][r] * sc + sh;
                v = (v >= 0.f) ? v : 0.1f * v;
                outb[(size_t)o * HW_ + col] = v;
            }
        }
}

extern "C" void kernel_launch(void* const* d_in, const int* in_sizes, int n_in,
                              void* d_out, int out_size, void* d_ws, size_t ws_size,
                              hipStream_t stream) {
    const float* x      = (const float*)d_in[0];
    const float* p_w    = (const float*)d_in[1];
    const float* p_b    = (const float*)d_in[2];
    const float* w_conv = (const float*)d_in[3];
    const float* gamma  = (const float*)d_in[4];
    const float* beta   = (const float*)d_in[5];
    float* out = (float*)d_out;

    char* wsb = (char*)d_ws;
    unsigned short* xpad  = (unsigned short*)wsb;
    float*          offT  = (float*)(wsb + OFF_BYTE);
    unsigned short* wrepb = (unsigned short*)(wsb + WREPB_BYTE);
    float*          stats = (float*)(wsb + STATS_BYTE);
    short*          wofff = (short*)(wsb + WOFF_BYTE);

    hipMemsetAsync(xpad, 0, (size_t)XPAD_BYTES, stream);
    hipMemsetAsync(stats, 0, 4096, stream);

    k_transpose<<<dim3(W_ / 32, C_ / 32, B_ * H_), dim3(32, 8), 0, stream>>>(x, xpad);
    k_repackA<<<dim3((9 * 4096 + 9 * C_ * O_ + 255) / 256), 256, 0, stream>>>(p_w, wofff, w_conv, wrepb);
    k_offconv<<<dim3(2, H_, B_), 256, 0, stream>>>(xpad, wofff, p_b, offT);
    k_main<<<dim3(512), 512, 0, stream>>>(xpad, offT, wrepb, out, stats, gamma, beta);
}

// Round 5
// 228.460 us; speedup vs baseline: 1.1004x; 1.0996x over previous
//
#include <hip/hip_runtime.h>
#include <cstdint>

typedef __attribute__((ext_vector_type(8))) short bf16x8;
typedef __attribute__((ext_vector_type(4))) float f32x4;

#define B_   4
#define C_   128
#define H_   128
#define W_   128
#define HP_  130
#define WP_  130
#define O_   256
#define HW_  (H_*W_)          // 16384

// ws layout (byte offsets)
#define XPAD_BYTES   (B_*HP_*WP_*C_*2)          // bf16 xpad: 17,305,600
#define OFF_BYTE     XPAD_BYTES
#define OFF_BYTES    (B_*HW_*18*4)              // 4,718,592
#define WREPB_BYTE   (OFF_BYTE + OFF_BYTES)
#define WREPB_BYTES  (9*C_*O_*2)                // 589,824
#define STATS_BYTE   (WREPB_BYTE + WREPB_BYTES)
#define WOFF_BYTE    (STATS_BYTE + 4096)
#define WOFF_BYTES   (9*4*4*32*8*2)             // 73,728

typedef __attribute__((address_space(1))) const void gconst_void;
typedef __attribute__((address_space(3))) void lds_void;
#define GLD_LDS16(gp, lp) __builtin_amdgcn_global_load_lds((gconst_void*)(gp), (lds_void*)(lp), 16, 0, 0)

__device__ __forceinline__ unsigned pack_bf2(float a, float b) {
    unsigned ua = __builtin_bit_cast(unsigned, a) + 0x8000u;
    unsigned ub = __builtin_bit_cast(unsigned, b) + 0x8000u;
    return __builtin_amdgcn_perm(ub, ua, 0x07060302u);
}

// ---------------- K1: NCHW fp32 -> padded NHWC bf16 transpose ----------------
__global__ void k_transpose(const float* __restrict__ x, unsigned short* __restrict__ xpad) {
    __shared__ float tile[32][33];   // [c_loc][w_loc]
    int w0 = blockIdx.x * 32, c0 = blockIdx.y * 32;
    int bh = blockIdx.z;
    int b = bh >> 7, h = bh & 127;
    int tx = threadIdx.x, ty = threadIdx.y;
#pragma unroll
    for (int i = 0; i < 4; i++) {
        int c = c0 + ty + i * 8;
        tile[ty + i * 8][tx] = x[((b * C_ + c) * H_ + h) * W_ + w0 + tx];
    }
    __syncthreads();
    int tid = ty * 32 + tx;
    int cp = tid & 15;
    int wl = tid >> 4;
#pragma unroll
    for (int i = 0; i < 2; i++) {
        int wll = wl + i * 16;
        int w = w0 + wll;
        unsigned v = pack_bf2(tile[2 * cp][wll], tile[2 * cp + 1][wll]);
        *(unsigned*)(&xpad[((size_t)((b * HP_ + h + 1) * WP_ + (w + 1))) * C_ + c0 + 2 * cp]) = v;
    }
}

// ---------------- K2ab fused: repack p_w -> wofff AND w_conv -> wrepb ----------------
__global__ void k_repackA(const float* __restrict__ p_w, short* __restrict__ wofff,
                          const float* __restrict__ w_conv, unsigned short* __restrict__ wrepb) {
    int i = blockIdx.x * 256 + threadIdx.x;
    if (i < 9 * 4096) {
        int e = i & 7, m = (i >> 3) & 31, q = (i >> 8) & 3, kc = (i >> 10) & 3, tap = i >> 12;
        float f = (m < 18) ? p_w[((size_t)m * C_ + kc * 32 + q * 8 + e) * 9 + tap] : 0.f;
        unsigned u = __builtin_bit_cast(unsigned, f);
        u += 0x7fffu + ((u >> 16) & 1u);   // RNE
        wofff[i] = (short)(u >> 16);
    }
    int j = i - 9 * 4096;
    if (j >= 0 && j < 9 * C_ * O_) {
        int ki8 = j & 7;
        int o   = (j >> 3) & 255;
        int kq  = (j >> 11) & 3;
        int kc  = (j >> 13) & 3;
        int n   = j >> 15;
        int c = kc * 32 + kq * 8 + ki8;
        float f = w_conv[(o * C_ + c) * 9 + n];
        unsigned u = __builtin_bit_cast(unsigned, f);
        u += 0x7fffu + ((u >> 16) & 1u);   // RNE
        wrepb[j] = (unsigned short)(u >> 16);
    }
}

// ---------------- K2: offset conv as MFMA GEMM (M=18 pad 32, K=1152) ----------------
__global__ __launch_bounds__(256) void k_offconv(const unsigned short* __restrict__ xpad,
                                                 const short* __restrict__ wofff,
                                                 const float* __restrict__ p_b,
                                                 float* __restrict__ offT) {
    int t = threadIdx.x;
    int ph = blockIdx.x;
    int h  = blockIdx.y;
    int b  = blockIdx.z;
    const unsigned short* xb = xpad + (size_t)b * HP_ * WP_ * C_;
    int lane = t & 63, wv = t >> 6;
    int q = lane >> 4, l15 = lane & 15;
    int pos0 = ph * 64 + wv * 16;
    int poscol = pos0 + l15;

    f32x4 accA = {0.f, 0.f, 0.f, 0.f}, accB = {0.f, 0.f, 0.f, 0.f};
    const bf16x8* Wf = (const bf16x8*)wofff;

    for (int tap = 0; tap < 9; tap++) {
        int row = h + tap / 3;
        int col = poscol + tap % 3;
        const unsigned short* src = xb + ((size_t)(row * WP_ + col)) * C_ + q * 8;
#pragma unroll
        for (int kc = 0; kc < 4; kc++) {
            bf16x8 a0 = Wf[(size_t)(((tap * 4 + kc) * 4 + q) * 32) + l15];
            bf16x8 a1 = Wf[(size_t)(((tap * 4 + kc) * 4 + q) * 32) + 16 + l15];
            bf16x8 bv = *(const bf16x8*)(src + kc * 32);
            accA = __builtin_amdgcn_mfma_f32_16x16x32_bf16(a0, bv, accA, 0, 0, 0);
            accB = __builtin_amdgcn_mfma_f32_16x16x32_bf16(a1, bv, accB, 0, 0, 0);
        }
    }
    size_t hw = (size_t)h * W_ + pos0 + l15;
#pragma unroll
    for (int r = 0; r < 4; r++) {
        int j = q * 4 + r;
        offT[((size_t)(b * 18 + j)) * HW_ + hw] = accA[r] + p_b[j];
    }
    if (q == 0) {
#pragma unroll
        for (int r = 0; r < 2; r++) {
            int j = 16 + r;
            offT[((size_t)(b * 18 + j)) * HW_ + hw] = accB[r] + p_b[j];
        }
    }
}

// ---------------- K3: one block per (b,h); R1 proven pipeline (1 barrier/step, implicit sync) ----------------
__global__ __launch_bounds__(512, 4) void k_main(const unsigned short* __restrict__ xpad,
                                                 const float* __restrict__ offT,
                                                 const unsigned short* __restrict__ wrepb,
                                                 float* __restrict__ out,
                                                 float* __restrict__ stats) {
    __shared__ short Wl[2][8192];        // double-buffered W chunk, 32 KB
    __shared__ short Vl[2][4128];        // double-buffered skewed V, 16.1 KB
    __shared__ int   pbase[2][4][128];   // tap-parity double buffer, 4 KB
    __shared__ float pg[2][4][128];      // 4 KB
    __shared__ float red0[256], red1[256];

    int t = threadIdx.x;
    int i_blk = blockIdx.x;
    int b = i_blk & 3;                   // XCD k serves b = k&3 only (round-robin heuristic)
    int h = i_blk >> 2;
    const unsigned short* xb = xpad + (size_t)b * HP_ * WP_ * C_;

    int lane = t & 63, wv = t >> 6;      // 8 waves
    int q = lane >> 4, l15 = lane & 15;
    int m0 = (wv & 3) * 64;              // o-slice
    int ph = wv >> 2;                    // pos half
    int n0 = ph * 64;
    int c4g = t & 3, posb = t >> 2;      // gather: 4 ch-subquads x 128 pos

    auto OFFSETS = [&](int n, int pb) {
        if (t < 128) {
            int w = t;
            float offx = offT[((size_t)(b * 18 + n)) * HW_ + h * W_ + w];
            float offy = offT[((size_t)(b * 18 + 9 + n)) * HW_ + h * W_ + w];
            int dxn = n / 3 - 1, dyn = n % 3 - 1;
            float px = (float)(h + 1 + dxn) + offx;
            float py = (float)(w + 1 + dyn) + offy;
            float pcx = fminf(fmaxf(px, 0.f), 129.f);
            float pcy = fminf(fmaxf(py, 0.f), 129.f);
            float fx = floorf(px), fy = floorf(py);
            float q0x = fminf(fmaxf(fx, 0.f), 129.f);
            float q0y = fminf(fmaxf(fy, 0.f), 129.f);
            float q1x = fminf(fmaxf(fx + 1.f, 0.f), 129.f);
            float q1y = fminf(fmaxf(fy + 1.f, 0.f), 129.f);
            float wx0 = 1.f + (q0x - pcx), wx1 = 1.f - (q1x - pcx);
            float wy0 = 1.f + (q0y - pcy), wy1 = 1.f - (q1y - pcy);
            int i0x = (int)q0x, i0y = (int)q0y, i1x = (int)q1x, i1y = (int)q1y;
            pbase[pb][0][w] = (i0x * WP_ + i0y) * C_;
            pbase[pb][1][w] = (i1x * WP_ + i1y) * C_;
            pbase[pb][2][w] = (i0x * WP_ + i1y) * C_;
            pbase[pb][3][w] = (i1x * WP_ + i0y) * C_;
            pg[pb][0][w] = wx0 * wy0;
            pg[pb][1][w] = wx1 * wy1;
            pg[pb][2][w] = wx0 * wy1;
            pg[pb][3][w] = wx1 * wy0;
        }
    };

    f32x4 acc[4][4];
#pragma unroll
    for (int i = 0; i < 4; i++)
#pragma unroll
        for (int j = 0; j < 4; j++) acc[i][j] = (f32x4){0.f, 0.f, 0.f, 0.f};

    if (t < 256) { red0[t] = 0.f; red1[t] = 0.f; }   // hoisted epilogue init (inert during loop)
    OFFSETS(0, 0);
    __syncthreads();

    // ---- prologue: stage step 0 into buffer 0 ----
    {
        const unsigned short* ws = wrepb;            // chunk 0
        GLD_LDS16(ws + (size_t)t * 8, &Wl[0][wv * 512]);
        GLD_LDS16(ws + (size_t)(t + 512) * 8, &Wl[0][wv * 512 + 4096]);
        int cof = c4g * 8;                           // kc=0
        uint4 A  = *(const uint4*)(xb + pbase[0][0][posb] + cof);
        uint4 Bv = *(const uint4*)(xb + pbase[0][1][posb] + cof);
        uint4 Cv = *(const uint4*)(xb + pbase[0][2][posb] + cof);
        uint4 Dv = *(const uint4*)(xb + pbase[0][3][posb] + cof);
        float g0 = pg[0][0][posb], g1 = pg[0][1][posb], g2 = pg[0][2][posb], g3 = pg[0][3][posb];
        unsigned outw[4];
#pragma unroll
        for (int k = 0; k < 4; k++) {
            unsigned ua = (&A.x)[k], ub = (&Bv.x)[k], uc = (&Cv.x)[k], ud = (&Dv.x)[k];
            float alo = __builtin_bit_cast(float, ua << 16), ahi = __builtin_bit_cast(float, ua & 0xffff0000u);
            float blo = __builtin_bit_cast(float, ub << 16), bhi = __builtin_bit_cast(float, ub & 0xffff0000u);
            float clo = __builtin_bit_cast(float, uc << 16), chi = __builtin_bit_cast(float, uc & 0xffff0000u);
            float dlo = __builtin_bit_cast(float, ud << 16), dhi = __builtin_bit_cast(float, ud & 0xffff0000u);
            float vlo = g0 * alo + g1 * blo + g2 * clo + g3 * dlo;
            float vhi = g0 * ahi + g1 * bhi + g2 * chi + g3 * dhi;
            outw[k] = pack_bf2(vlo, vhi);
        }
        *(uint4*)&Vl[0][(unsigned)(c4g * 129 + posb) * 8] = make_uint4(outw[0], outw[1], outw[2], outw[3]);
    }
    __syncthreads();

    // ---- main pipelined loop: 36 steps, 1 barrier per step (R1 proven structure) ----
#pragma unroll 1
    for (int s = 0; s < 36; s++) {
        int cur = s & 1, nxt = cur ^ 1;
        uint4 A, Bv, Cv, Dv;
        float g0 = 0.f, g1 = 0.f, g2 = 0.f, g3 = 0.f;
        bool st = (s < 35);
        if (st) {
            int s1 = s + 1;
            const unsigned short* ws = wrepb + (size_t)s1 * 8192;
            GLD_LDS16(ws + (size_t)t * 8, &Wl[nxt][wv * 512]);
            GLD_LDS16(ws + (size_t)(t + 512) * 8, &Wl[nxt][wv * 512 + 4096]);
            int n1 = s1 >> 2, kc1 = s1 & 3, pb1 = n1 & 1;
            int cof = kc1 * 32 + c4g * 8;
            A  = *(const uint4*)(xb + pbase[pb1][0][posb] + cof);
            Bv = *(const uint4*)(xb + pbase[pb1][1][posb] + cof);
            Cv = *(const uint4*)(xb + pbase[pb1][2][posb] + cof);
            Dv = *(const uint4*)(xb + pbase[pb1][3][posb] + cof);
            g0 = pg[pb1][0][posb]; g1 = pg[pb1][1][posb];
            g2 = pg[pb1][2][posb]; g3 = pg[pb1][3][posb];
        }
        // consume step s: loads for s+1 are in flight underneath the MFMAs
        {
            const bf16x8* Af = (const bf16x8*)Wl[cur];
            const bf16x8* Bf = (const bf16x8*)Vl[cur];
            bf16x8 av[4];
#pragma unroll
            for (int i = 0; i < 4; i++) av[i] = Af[q * 256 + m0 + i * 16 + l15];
            __builtin_amdgcn_s_setprio(1);
#pragma unroll
            for (int j = 0; j < 4; j++) {
                bf16x8 bv = Bf[q * 129 + n0 + j * 16 + l15];
#pragma unroll
                for (int i = 0; i < 4; i++)
                    acc[i][j] = __builtin_amdgcn_mfma_f32_16x16x32_bf16(av[i], bv, acc[i][j], 0, 0, 0);
            }
            __builtin_amdgcn_s_setprio(0);
        }
        // compute offsets one tap ahead (off the critical path, disjoint pb buffer)
        if ((s & 3) == 2) {
            int n = s >> 2;
            if (n < 8) OFFSETS(n + 1, (n + 1) & 1);
        }
        if (st) {
            unsigned outw[4];
#pragma unroll
            for (int k = 0; k < 4; k++) {
                unsigned ua = (&A.x)[k], ub = (&Bv.x)[k], uc = (&Cv.x)[k], ud = (&Dv.x)[k];
                float alo = __builtin_bit_cast(float, ua << 16), ahi = __builtin_bit_cast(float, ua & 0xffff0000u);
                float blo = __builtin_bit_cast(float, ub << 16), bhi = __builtin_bit_cast(float, ub & 0xffff0000u);
                float clo = __builtin_bit_cast(float, uc << 16), chi = __builtin_bit_cast(float, uc & 0xffff0000u);
                float dlo = __builtin_bit_cast(float, ud << 16), dhi = __builtin_bit_cast(float, ud & 0xffff0000u);
                float vlo = g0 * alo + g1 * blo + g2 * clo + g3 * dlo;
                float vhi = g0 * ahi + g1 * bhi + g2 * chi + g3 * dhi;
                outw[k] = pack_bf2(vlo, vhi);
            }
            *(uint4*)&Vl[nxt][(unsigned)(c4g * 129 + posb) * 8] = make_uint4(outw[0], outw[1], outw[2], outw[3]);
        }
        __syncthreads();
    }

    // ---- epilogue: BN partial sums ----
#pragma unroll
    for (int i = 0; i < 4; i++) {
#pragma unroll
        for (int r = 0; r < 4; r++) {
            int o_loc = m0 + i * 16 + q * 4 + r;
            float s = 0.f, s2 = 0.f;
#pragma unroll
            for (int j = 0; j < 4; j++) { float v = acc[i][j][r]; s += v; s2 += v * v; }
            s  += __shfl_xor(s, 1);  s  += __shfl_xor(s, 2);  s  += __shfl_xor(s, 4);  s  += __shfl_xor(s, 8);
            s2 += __shfl_xor(s2, 1); s2 += __shfl_xor(s2, 2); s2 += __shfl_xor(s2, 4); s2 += __shfl_xor(s2, 8);
            if (l15 == 0) { atomicAdd(&red0[o_loc], s); atomicAdd(&red1[o_loc], s2); }
        }
    }
    __syncthreads();
    if (t < 256) {
        atomicAdd(&stats[t], red0[t]);
        atomicAdd(&stats[256 + t], red1[t]);
    }

    // ---- epilogue: direct C write (64B segments per 16-lane group; L2 write-combines) ----
    float* outb = out + ((size_t)b * O_) * HW_ + (size_t)h * W_;
#pragma unroll
    for (int i = 0; i < 4; i++)
#pragma unroll
        for (int j = 0; j < 4; j++) {
            int col = ph * 64 + j * 16 + l15;
#pragma unroll
            for (int r = 0; r < 4; r++) {
                int o = m0 + i * 16 + q * 4 + r;
                outb[(size_t)o * HW_ + col] = acc[i][j][r];
            }
        }
}

// ---------------- K4: BN stats finalize ----------------
__global__ void k_bnstats(float* __restrict__ stats,
                          const float* __restrict__ gamma,
                          const float* __restrict__ beta) {
    int t = threadIdx.x;  // 256
    float s = stats[t], s2 = stats[256 + t];
    float mean = s * (1.f / 65536.f);
    float var = s2 * (1.f / 65536.f) - mean * mean;
    float sc = gamma[t] * rsqrtf(var + 1e-5f);
    float sh = beta[t] - mean * sc;
    stats[512 + t] = sc;
    stats[768 + t] = sh;
}

// ---------------- K5: normalize + leaky ReLU (in-place on d_out) ----------------
__global__ __launch_bounds__(256) void k_apply(float* __restrict__ out,
                                               const float* __restrict__ stats) {
    int idx = blockIdx.x * 256 + threadIdx.x;
    int e = idx * 4;
    int o = (e >> 14) & 255;
    float sc = stats[512 + o], sh = stats[768 + o];
    float4 v = *(float4*)(out + e);
    v.x = v.x * sc + sh; v.x = (v.x >= 0.f) ? v.x : 0.1f * v.x;
    v.y = v.y * sc + sh; v.y = (v.y >= 0.f) ? v.y : 0.1f * v.y;
    v.z = v.z * sc + sh; v.z = (v.z >= 0.f) ? v.z : 0.1f * v.z;
    v.w = v.w * sc + sh; v.w = (v.w >= 0.f) ? v.w : 0.1f * v.w;
    *(float4*)(out + e) = v;
}

extern "C" void kernel_launch(void* const* d_in, const int* in_sizes, int n_in,
                              void* d_out, int out_size, void* d_ws, size_t ws_size,
                              hipStream_t stream) {
    const float* x      = (const float*)d_in[0];
    const float* p_w    = (const float*)d_in[1];
    const float* p_b    = (const float*)d_in[2];
    const float* w_conv = (const float*)d_in[3];
    const float* gamma  = (const float*)d_in[4];
    const float* beta   = (const float*)d_in[5];
    float* out = (float*)d_out;

    char* wsb = (char*)d_ws;
    unsigned short* xpad  = (unsigned short*)wsb;
    float*          offT  = (float*)(wsb + OFF_BYTE);
    unsigned short* wrepb = (unsigned short*)(wsb + WREPB_BYTE);
    float*          stats = (float*)(wsb + STATS_BYTE);
    short*          wofff = (short*)(wsb + WOFF_BYTE);

    hipMemsetAsync(xpad, 0, (size_t)XPAD_BYTES, stream);
    hipMemsetAsync(stats, 0, 4096, stream);

    k_transpose<<<dim3(W_ / 32, C_ / 32, B_ * H_), dim3(32, 8), 0, stream>>>(x, xpad);
    k_repackA<<<dim3((9 * 4096 + 9 * C_ * O_ + 255) / 256), 256, 0, stream>>>(p_w, wofff, w_conv, wrepb);
    k_offconv<<<dim3(2, H_, B_), 256, 0, stream>>>(xpad, wofff, p_b, offT);
    k_main<<<dim3(512), 512, 0, stream>>>(xpad, offT, wrepb, out, stats);
    k_bnstats<<<1, 256, 0, stream>>>(stats, gamma, beta);
    k_apply<<<dim3(16384), 256, 0, stream>>>(out, stats);
}

// Round 6
// 218.022 us; speedup vs baseline: 1.1531x; 1.0479x over previous
//
#include <hip/hip_runtime.h>
#include <cstdint>

typedef __attribute__((ext_vector_type(8))) short bf16x8;
typedef __attribute__((ext_vector_type(4))) float f32x4;

#define B_   4
#define C_   128
#define H_   128
#define W_   128
#define HP_  130
#define WP_  130
#define O_   256
#define HW_  (H_*W_)          // 16384

// ws layout (byte offsets)
#define XPAD_BYTES   (B_*HP_*WP_*C_*2)          // bf16 xpad: 17,305,600
#define OFF_BYTE     XPAD_BYTES
#define OFF_BYTES    (B_*HW_*18*4)              // 4,718,592
#define WREPB_BYTE   (OFF_BYTE + OFF_BYTES)
#define WREPB_BYTES  (9*C_*O_*2)                // 589,824
#define STATS_BYTE   (WREPB_BYTE + WREPB_BYTES)
#define WOFF_BYTE    (STATS_BYTE + 4096)
#define WOFF_BYTES   (9*4*4*32*8*2)             // 73,728

typedef __attribute__((address_space(1))) const void gconst_void;
typedef __attribute__((address_space(3))) void lds_void;
#define GLD_LDS16(gp, lp) __builtin_amdgcn_global_load_lds((gconst_void*)(gp), (lds_void*)(lp), 16, 0, 0)

__device__ __forceinline__ unsigned pack_bf2(float a, float b) {
    unsigned ua = __builtin_bit_cast(unsigned, a) + 0x8000u;
    unsigned ub = __builtin_bit_cast(unsigned, b) + 0x8000u;
    return __builtin_amdgcn_perm(ub, ua, 0x07060302u);
}

// ---------------- K1: NCHW fp32 -> padded NHWC bf16 transpose + ring zeroing ----------------
__global__ void k_transpose(const float* __restrict__ x, unsigned short* __restrict__ xpad) {
    __shared__ float tile[32][33];   // [c_loc][w_loc]
    int w0 = blockIdx.x * 32, c0 = blockIdx.y * 32;
    int bh = blockIdx.z;
    int b = bh >> 7, h = bh & 127;
    int tx = threadIdx.x, ty = threadIdx.y;
#pragma unroll
    for (int i = 0; i < 4; i++) {
        int c = c0 + ty + i * 8;
        tile[ty + i * 8][tx] = x[((b * C_ + c) * H_ + h) * W_ + w0 + tx];
    }
    int tid = ty * 32 + tx;
    // ---- padding-ring zeroing (replaces the 17.3 MB memset; interior is fully overwritten) ----
    if (h == 0) {
        // rows hp=0 and hp=129, wp = w0+1..w0+32, this c-tile: 8 B per thread per row
        int wloc = tid >> 3, cq = tid & 7;
        size_t r0 = ((size_t)(b * HP_ + 0)   * WP_ + (w0 + 1 + wloc)) * C_ + c0 + cq * 4;
        size_t r1 = ((size_t)(b * HP_ + 129) * WP_ + (w0 + 1 + wloc)) * C_ + c0 + cq * 4;
        *(uint2*)&xpad[r0] = make_uint2(0u, 0u);
        *(uint2*)&xpad[r1] = make_uint2(0u, 0u);
        if (w0 == 0 && tid < 128) {
            // 4 corners (hp in {0,129} x wp in {0,129}), 32 ch of this c-tile
            int corner = tid >> 5, cc = tid & 31;
            int hp = (corner & 1) ? 129 : 0;
            int wp = (corner & 2) ? 129 : 0;
            xpad[((size_t)(b * HP_ + hp) * WP_ + wp) * C_ + c0 + cc] = 0;
        }
    }
    if (w0 == 0 && tid < 64) {
        // cols wp=0 and wp=129 at hp=h+1, 32 ch of this c-tile
        int side = tid >> 5, cc = tid & 31;
        int wp = side ? 129 : 0;
        xpad[((size_t)(b * HP_ + h + 1) * WP_ + wp) * C_ + c0 + cc] = 0;
    }
    __syncthreads();
    // ---- wide store phase: 128 x uint4 (16 B per store, 64 B runs per w) ----
    if (tid < 128) {
        int w = tid >> 2, u4 = tid & 3;
        unsigned r0 = pack_bf2(tile[8 * u4 + 0][w], tile[8 * u4 + 1][w]);
        unsigned r1 = pack_bf2(tile[8 * u4 + 2][w], tile[8 * u4 + 3][w]);
        unsigned r2 = pack_bf2(tile[8 * u4 + 4][w], tile[8 * u4 + 5][w]);
        unsigned r3 = pack_bf2(tile[8 * u4 + 6][w], tile[8 * u4 + 7][w]);
        *(uint4*)&xpad[((size_t)((b * HP_ + h + 1) * WP_ + (w0 + w + 1))) * C_ + c0 + u4 * 8] =
            make_uint4(r0, r1, r2, r3);
    }
}

// ---------------- K2ab fused: repack p_w -> wofff AND w_conv -> wrepb AND zero stats ----------------
__global__ void k_repackA(const float* __restrict__ p_w, short* __restrict__ wofff,
                          const float* __restrict__ w_conv, unsigned short* __restrict__ wrepb,
                          float* __restrict__ stats) {
    int i = blockIdx.x * 256 + threadIdx.x;
    if (i < 1024) stats[i] = 0.f;       // replaces the stats memset
    if (i < 9 * 4096) {
        int e = i & 7, m = (i >> 3) & 31, q = (i >> 8) & 3, kc = (i >> 10) & 3, tap = i >> 12;
        float f = (m < 18) ? p_w[((size_t)m * C_ + kc * 32 + q * 8 + e) * 9 + tap] : 0.f;
        unsigned u = __builtin_bit_cast(unsigned, f);
        u += 0x7fffu + ((u >> 16) & 1u);   // RNE
        wofff[i] = (short)(u >> 16);
    }
    int j = i - 9 * 4096;
    if (j >= 0 && j < 9 * C_ * O_) {
        int ki8 = j & 7;
        int o   = (j >> 3) & 255;
        int kq  = (j >> 11) & 3;
        int kc  = (j >> 13) & 3;
        int n   = j >> 15;
        int c = kc * 32 + kq * 8 + ki8;
        float f = w_conv[(o * C_ + c) * 9 + n];
        unsigned u = __builtin_bit_cast(unsigned, f);
        u += 0x7fffu + ((u >> 16) & 1u);   // RNE
        wrepb[j] = (unsigned short)(u >> 16);
    }
}

// ---------------- K2: offset conv as MFMA GEMM (M=18 pad 32, K=1152) ----------------
__global__ __launch_bounds__(256) void k_offconv(const unsigned short* __restrict__ xpad,
                                                 const short* __restrict__ wofff,
                                                 const float* __restrict__ p_b,
                                                 float* __restrict__ offT) {
    int t = threadIdx.x;
    int ph = blockIdx.x;
    int h  = blockIdx.y;
    int b  = blockIdx.z;
    const unsigned short* xb = xpad + (size_t)b * HP_ * WP_ * C_;
    int lane = t & 63, wv = t >> 6;
    int q = lane >> 4, l15 = lane & 15;
    int pos0 = ph * 64 + wv * 16;
    int poscol = pos0 + l15;

    f32x4 accA = {0.f, 0.f, 0.f, 0.f}, accB = {0.f, 0.f, 0.f, 0.f};
    const bf16x8* Wf = (const bf16x8*)wofff;

    for (int tap = 0; tap < 9; tap++) {
        int row = h + tap / 3;
        int col = poscol + tap % 3;
        const unsigned short* src = xb + ((size_t)(row * WP_ + col)) * C_ + q * 8;
#pragma unroll
        for (int kc = 0; kc < 4; kc++) {
            bf16x8 a0 = Wf[(size_t)(((tap * 4 + kc) * 4 + q) * 32) + l15];
            bf16x8 a1 = Wf[(size_t)(((tap * 4 + kc) * 4 + q) * 32) + 16 + l15];
            bf16x8 bv = *(const bf16x8*)(src + kc * 32);
            accA = __builtin_amdgcn_mfma_f32_16x16x32_bf16(a0, bv, accA, 0, 0, 0);
            accB = __builtin_amdgcn_mfma_f32_16x16x32_bf16(a1, bv, accB, 0, 0, 0);
        }
    }
    size_t hw = (size_t)h * W_ + pos0 + l15;
#pragma unroll
    for (int r = 0; r < 4; r++) {
        int j = q * 4 + r;
        offT[((size_t)(b * 18 + j)) * HW_ + hw] = accA[r] + p_b[j];
    }
    if (q == 0) {
#pragma unroll
        for (int r = 0; r < 2; r++) {
            int j = 16 + r;
            offT[((size_t)(b * 18 + j)) * HW_ + hw] = accB[r] + p_b[j];
        }
    }
}

// ---------------- K3: one block per (b,h); R1 proven pipeline (1 barrier/step, implicit sync) ----------------
__global__ __launch_bounds__(512, 4) void k_main(const unsigned short* __restrict__ xpad,
                                                 const float* __restrict__ offT,
                                                 const unsigned short* __restrict__ wrepb,
                                                 float* __restrict__ out,
                                                 float* __restrict__ stats) {
    __shared__ short Wl[2][8192];        // double-buffered W chunk, 32 KB
    __shared__ short Vl[2][4128];        // double-buffered skewed V, 16.1 KB
    __shared__ int   pbase[2][4][128];   // tap-parity double buffer, 4 KB
    __shared__ float pg[2][4][128];      // 4 KB
    __shared__ float red0[256], red1[256];

    int t = threadIdx.x;
    int i_blk = blockIdx.x;
    int b = i_blk & 3;                   // XCD k serves b = k&3 only (round-robin heuristic)
    int h = i_blk >> 2;
    const unsigned short* xb = xpad + (size_t)b * HP_ * WP_ * C_;

    int lane = t & 63, wv = t >> 6;      // 8 waves
    int q = lane >> 4, l15 = lane & 15;
    int m0 = (wv & 3) * 64;              // o-slice
    int ph = wv >> 2;                    // pos half
    int n0 = ph * 64;
    int c4g = t & 3, posb = t >> 2;      // gather: 4 ch-subquads x 128 pos

    auto OFFSETS = [&](int n, int pb) {
        if (t < 128) {
            int w = t;
            float offx = offT[((size_t)(b * 18 + n)) * HW_ + h * W_ + w];
            float offy = offT[((size_t)(b * 18 + 9 + n)) * HW_ + h * W_ + w];
            int dxn = n / 3 - 1, dyn = n % 3 - 1;
            float px = (float)(h + 1 + dxn) + offx;
            float py = (float)(w + 1 + dyn) + offy;
            float pcx = fminf(fmaxf(px, 0.f), 129.f);
            float pcy = fminf(fmaxf(py, 0.f), 129.f);
            float fx = floorf(px), fy = floorf(py);
            float q0x = fminf(fmaxf(fx, 0.f), 129.f);
            float q0y = fminf(fmaxf(fy, 0.f), 129.f);
            float q1x = fminf(fmaxf(fx + 1.f, 0.f), 129.f);
            float q1y = fminf(fmaxf(fy + 1.f, 0.f), 129.f);
            float wx0 = 1.f + (q0x - pcx), wx1 = 1.f - (q1x - pcx);
            float wy0 = 1.f + (q0y - pcy), wy1 = 1.f - (q1y - pcy);
            int i0x = (int)q0x, i0y = (int)q0y, i1x = (int)q1x, i1y = (int)q1y;
            pbase[pb][0][w] = (i0x * WP_ + i0y) * C_;
            pbase[pb][1][w] = (i1x * WP_ + i1y) * C_;
            pbase[pb][2][w] = (i0x * WP_ + i1y) * C_;
            pbase[pb][3][w] = (i1x * WP_ + i0y) * C_;
            pg[pb][0][w] = wx0 * wy0;
            pg[pb][1][w] = wx1 * wy1;
            pg[pb][2][w] = wx0 * wy1;
            pg[pb][3][w] = wx1 * wy0;
        }
    };

    f32x4 acc[4][4];
#pragma unroll
    for (int i = 0; i < 4; i++)
#pragma unroll
        for (int j = 0; j < 4; j++) acc[i][j] = (f32x4){0.f, 0.f, 0.f, 0.f};

    if (t < 256) { red0[t] = 0.f; red1[t] = 0.f; }   // hoisted epilogue init (inert during loop)
    OFFSETS(0, 0);
    __syncthreads();

    // ---- prologue: stage step 0 into buffer 0 ----
    {
        const unsigned short* ws = wrepb;            // chunk 0
        GLD_LDS16(ws + (size_t)t * 8, &Wl[0][wv * 512]);
        GLD_LDS16(ws + (size_t)(t + 512) * 8, &Wl[0][wv * 512 + 4096]);
        int cof = c4g * 8;                           // kc=0
        uint4 A  = *(const uint4*)(xb + pbase[0][0][posb] + cof);
        uint4 Bv = *(const uint4*)(xb + pbase[0][1][posb] + cof);
        uint4 Cv = *(const uint4*)(xb + pbase[0][2][posb] + cof);
        uint4 Dv = *(const uint4*)(xb + pbase[0][3][posb] + cof);
        float g0 = pg[0][0][posb], g1 = pg[0][1][posb], g2 = pg[0][2][posb], g3 = pg[0][3][posb];
        unsigned outw[4];
#pragma unroll
        for (int k = 0; k < 4; k++) {
            unsigned ua = (&A.x)[k], ub = (&Bv.x)[k], uc = (&Cv.x)[k], ud = (&Dv.x)[k];
            float alo = __builtin_bit_cast(float, ua << 16), ahi = __builtin_bit_cast(float, ua & 0xffff0000u);
            float blo = __builtin_bit_cast(float, ub << 16), bhi = __builtin_bit_cast(float, ub & 0xffff0000u);
            float clo = __builtin_bit_cast(float, uc << 16), chi = __builtin_bit_cast(float, uc & 0xffff0000u);
            float dlo = __builtin_bit_cast(float, ud << 16), dhi = __builtin_bit_cast(float, ud & 0xffff0000u);
            float vlo = g0 * alo + g1 * blo + g2 * clo + g3 * dlo;
            float vhi = g0 * ahi + g1 * bhi + g2 * chi + g3 * dhi;
            outw[k] = pack_bf2(vlo, vhi);
        }
        *(uint4*)&Vl[0][(unsigned)(c4g * 129 + posb) * 8] = make_uint4(outw[0], outw[1], outw[2], outw[3]);
    }
    __syncthreads();

    // ---- main pipelined loop: 36 steps, 1 barrier per step (R1 proven structure) ----
#pragma unroll 1
    for (int s = 0; s < 36; s++) {
        int cur = s & 1, nxt = cur ^ 1;
        uint4 A, Bv, Cv, Dv;
        float g0 = 0.f, g1 = 0.f, g2 = 0.f, g3 = 0.f;
        bool st = (s < 35);
        if (st) {
            int s1 = s + 1;
            const unsigned short* ws = wrepb + (size_t)s1 * 8192;
            GLD_LDS16(ws + (size_t)t * 8, &Wl[nxt][wv * 512]);
            GLD_LDS16(ws + (size_t)(t + 512) * 8, &Wl[nxt][wv * 512 + 4096]);
            int n1 = s1 >> 2, kc1 = s1 & 3, pb1 = n1 & 1;
            int cof = kc1 * 32 + c4g * 8;
            A  = *(const uint4*)(xb + pbase[pb1][0][posb] + cof);
            Bv = *(const uint4*)(xb + pbase[pb1][1][posb] + cof);
            Cv = *(const uint4*)(xb + pbase[pb1][2][posb] + cof);
            Dv = *(const uint4*)(xb + pbase[pb1][3][posb] + cof);
            g0 = pg[pb1][0][posb]; g1 = pg[pb1][1][posb];
            g2 = pg[pb1][2][posb]; g3 = pg[pb1][3][posb];
        }
        // consume step s: loads for s+1 are in flight underneath the MFMAs
        {
            const bf16x8* Af = (const bf16x8*)Wl[cur];
            const bf16x8* Bf = (const bf16x8*)Vl[cur];
            bf16x8 av[4];
#pragma unroll
            for (int i = 0; i < 4; i++) av[i] = Af[q * 256 + m0 + i * 16 + l15];
            __builtin_amdgcn_s_setprio(1);
#pragma unroll
            for (int j = 0; j < 4; j++) {
                bf16x8 bv = Bf[q * 129 + n0 + j * 16 + l15];
#pragma unroll
                for (int i = 0; i < 4; i++)
                    acc[i][j] = __builtin_amdgcn_mfma_f32_16x16x32_bf16(av[i], bv, acc[i][j], 0, 0, 0);
            }
            __builtin_amdgcn_s_setprio(0);
        }
        // compute offsets one tap ahead (off the critical path, disjoint pb buffer)
        if ((s & 3) == 2) {
            int n = s >> 2;
            if (n < 8) OFFSETS(n + 1, (n + 1) & 1);
        }
        if (st) {
            unsigned outw[4];
#pragma unroll
            for (int k = 0; k < 4; k++) {
                unsigned ua = (&A.x)[k], ub = (&Bv.x)[k], uc = (&Cv.x)[k], ud = (&Dv.x)[k];
                float alo = __builtin_bit_cast(float, ua << 16), ahi = __builtin_bit_cast(float, ua & 0xffff0000u);
                float blo = __builtin_bit_cast(float, ub << 16), bhi = __builtin_bit_cast(float, ub & 0xffff0000u);
                float clo = __builtin_bit_cast(float, uc << 16), chi = __builtin_bit_cast(float, uc & 0xffff0000u);
                float dlo = __builtin_bit_cast(float, ud << 16), dhi = __builtin_bit_cast(float, ud & 0xffff0000u);
                float vlo = g0 * alo + g1 * blo + g2 * clo + g3 * dlo;
                float vhi = g0 * ahi + g1 * bhi + g2 * chi + g3 * dhi;
                outw[k] = pack_bf2(vlo, vhi);
            }
            *(uint4*)&Vl[nxt][(unsigned)(c4g * 129 + posb) * 8] = make_uint4(outw[0], outw[1], outw[2], outw[3]);
        }
        __syncthreads();
    }

    // ---- epilogue: BN partial sums ----
#pragma unroll
    for (int i = 0; i < 4; i++) {
#pragma unroll
        for (int r = 0; r < 4; r++) {
            int o_loc = m0 + i * 16 + q * 4 + r;
            float s = 0.f, s2 = 0.f;
#pragma unroll
            for (int j = 0; j < 4; j++) { float v = acc[i][j][r]; s += v; s2 += v * v; }
            s  += __shfl_xor(s, 1);  s  += __shfl_xor(s, 2);  s  += __shfl_xor(s, 4);  s  += __shfl_xor(s, 8);
            s2 += __shfl_xor(s2, 1); s2 += __shfl_xor(s2, 2); s2 += __shfl_xor(s2, 4); s2 += __shfl_xor(s2, 8);
            if (l15 == 0) { atomicAdd(&red0[o_loc], s); atomicAdd(&red1[o_loc], s2); }
        }
    }
    __syncthreads();
    if (t < 256) {
        atomicAdd(&stats[t], red0[t]);
        atomicAdd(&stats[256 + t], red1[t]);
    }

    // ---- epilogue: direct C write (64B segments per 16-lane group; L2 write-combines) ----
    float* outb = out + ((size_t)b * O_) * HW_ + (size_t)h * W_;
#pragma unroll
    for (int i = 0; i < 4; i++)
#pragma unroll
        for (int j = 0; j < 4; j++) {
            int col = ph * 64 + j * 16 + l15;
#pragma unroll
            for (int r = 0; r < 4; r++) {
                int o = m0 + i * 16 + q * 4 + r;
                outb[(size_t)o * HW_ + col] = acc[i][j][r];
            }
        }
}

// ---------------- K5: BN finalize (inline) + normalize + leaky ReLU (in-place on d_out) ----------------
__global__ __launch_bounds__(256) void k_apply(float* __restrict__ out,
                                               const float* __restrict__ stats,
                                               const float* __restrict__ gamma,
                                               const float* __restrict__ beta) {
    int idx = blockIdx.x * 256 + threadIdx.x;
    int e = idx * 4;
    int o = (e >> 14) & 255;             // uniform per block (1024 floats/block, 16384 floats/o)
    float s0 = stats[o], s2v = stats[256 + o];
    float mean = s0 * (1.f / 65536.f);
    float var = s2v * (1.f / 65536.f) - mean * mean;
    float sc = gamma[o] * rsqrtf(var + 1e-5f);
    float sh = beta[o] - mean * sc;
    float4 v = *(float4*)(out + e);
    v.x = v.x * sc + sh; v.x = (v.x >= 0.f) ? v.x : 0.1f * v.x;
    v.y = v.y * sc + sh; v.y = (v.y >= 0.f) ? v.y : 0.1f * v.y;
    v.z = v.z * sc + sh; v.z = (v.z >= 0.f) ? v.z : 0.1f * v.z;
    v.w = v.w * sc + sh; v.w = (v.w >= 0.f) ? v.w : 0.1f * v.w;
    *(float4*)(out + e) = v;
}

extern "C" void kernel_launch(void* const* d_in, const int* in_sizes, int n_in,
                              void* d_out, int out_size, void* d_ws, size_t ws_size,
                              hipStream_t stream) {
    const float* x      = (const float*)d_in[0];
    const float* p_w    = (const float*)d_in[1];
    const float* p_b    = (const float*)d_in[2];
    const float* w_conv = (const float*)d_in[3];
    const float* gamma  = (const float*)d_in[4];
    const float* beta   = (const float*)d_in[5];
    float* out = (float*)d_out;

    char* wsb = (char*)d_ws;
    unsigned short* xpad  = (unsigned short*)wsb;
    float*          offT  = (float*)(wsb + OFF_BYTE);
    unsigned short* wrepb = (unsigned short*)(wsb + WREPB_BYTE);
    float*          stats = (float*)(wsb + STATS_BYTE);
    short*          wofff = (short*)(wsb + WOFF_BYTE);

    k_transpose<<<dim3(W_ / 32, C_ / 32, B_ * H_), dim3(32, 8), 0, stream>>>(x, xpad);
    k_repackA<<<dim3((9 * 4096 + 9 * C_ * O_ + 255) / 256), 256, 0, stream>>>(p_w, wofff, w_conv, wrepb, stats);
    k_offconv<<<dim3(2, H_, B_), 256, 0, stream>>>(xpad, wofff, p_b, offT);
    k_main<<<dim3(512), 512, 0, stream>>>(xpad, offT, wrepb, out, stats);
    k_apply<<<dim3(16384), 256, 0, stream>>>(out, stats, gamma, beta);
}

// Round 7
// 214.916 us; speedup vs baseline: 1.1697x; 1.0145x over previous
//
#include <hip/hip_runtime.h>
#include <cstdint>

typedef __attribute__((ext_vector_type(8))) short bf16x8;
typedef __attribute__((ext_vector_type(4))) float f32x4;

#define B_   4
#define C_   128
#define H_   128
#define W_   128
#define HP_  130
#define WP_  130
#define O_   256
#define HW_  (H_*W_)          // 16384

// ws layout (byte offsets)
#define XPAD_BYTES   (B_*HP_*WP_*C_*2)          // bf16 xpad: 17,305,600
#define OFF_BYTE     XPAD_BYTES
#define OFF_BYTES    (B_*HW_*18*4)              // 4,718,592
#define WREPB_BYTE   (OFF_BYTE + OFF_BYTES)
#define WREPB_BYTES  (9*C_*O_*2)                // 589,824
#define STATS_BYTE   (WREPB_BYTE + WREPB_BYTES)
#define WOFF_BYTE    (STATS_BYTE + 4096)
#define WOFF_BYTES   (9*4*4*32*8*2)             // 73,728
#define RAW_BYTE     (WOFF_BYTE + WOFF_BYTES)   // 22,691,840 (256-aligned)
#define RAW_BYTES    ((size_t)B_*O_*HW_*2)      // 33,554,432 bf16 raw out
#define WS_NEED      ((size_t)RAW_BYTE + RAW_BYTES)

typedef __attribute__((address_space(1))) const void gconst_void;
typedef __attribute__((address_space(3))) void lds_void;
#define GLD_LDS16(gp, lp) __builtin_amdgcn_global_load_lds((gconst_void*)(gp), (lds_void*)(lp), 16, 0, 0)

__device__ __forceinline__ unsigned pack_bf2(float a, float b) {
    unsigned ua = __builtin_bit_cast(unsigned, a) + 0x8000u;
    unsigned ub = __builtin_bit_cast(unsigned, b) + 0x8000u;
    return __builtin_amdgcn_perm(ub, ua, 0x07060302u);
}

__device__ __forceinline__ unsigned short bf16_rne(float f) {
    unsigned u = __builtin_bit_cast(unsigned, f);
    u += 0x7fffu + ((u >> 16) & 1u);
    return (unsigned short)(u >> 16);
}

// ---------------- K1: NCHW fp32 -> padded NHWC bf16 transpose + ring zeroing + fused repack ----------------
__global__ void k_transpose(const float* __restrict__ x, unsigned short* __restrict__ xpad,
                            const float* __restrict__ p_w, short* __restrict__ wofff,
                            const float* __restrict__ w_conv, unsigned short* __restrict__ wrepb,
                            float* __restrict__ stats) {
    __shared__ float tile[32][33];   // [c_loc][w_loc]
    int w0 = blockIdx.x * 32, c0 = blockIdx.y * 32;
    int bh = blockIdx.z;
    int b = bh >> 7, h = bh & 127;
    int tx = threadIdx.x, ty = threadIdx.y;
#pragma unroll
    for (int i = 0; i < 4; i++) {
        int c = c0 + ty + i * 8;
        tile[ty + i * 8][tx] = x[((b * C_ + c) * H_ + h) * W_ + w0 + tx];
    }
    int tid = ty * 32 + tx;
    // ---- fused repack (first 1296 flat blocks): p_w->wofff, w_conv->wrepb, stats zero ----
    {
        int fb = (bh * 4 + (int)blockIdx.y) * 4 + (int)blockIdx.x;
        int i = fb * 256 + tid;
        if (i < 1024) stats[i] = 0.f;
        if (i < 9 * 4096) {
            int e = i & 7, m = (i >> 3) & 31, q = (i >> 8) & 3, kc = (i >> 10) & 3, tap = i >> 12;
            float f = (m < 18) ? p_w[((size_t)m * C_ + kc * 32 + q * 8 + e) * 9 + tap] : 0.f;
            wofff[i] = (short)bf16_rne(f);
        }
        int j = i - 9 * 4096;
        if (j >= 0 && j < 9 * C_ * O_) {
            int ki8 = j & 7;
            int o   = (j >> 3) & 255;
            int kq  = (j >> 11) & 3;
            int kc  = (j >> 13) & 3;
            int n   = j >> 15;
            int c = kc * 32 + kq * 8 + ki8;
            wrepb[j] = bf16_rne(w_conv[(o * C_ + c) * 9 + n]);
        }
    }
    // ---- padding-ring zeroing (interior is fully overwritten) ----
    if (h == 0) {
        int wloc = tid >> 3, cq = tid & 7;
        size_t r0 = ((size_t)(b * HP_ + 0)   * WP_ + (w0 + 1 + wloc)) * C_ + c0 + cq * 4;
        size_t r1 = ((size_t)(b * HP_ + 129) * WP_ + (w0 + 1 + wloc)) * C_ + c0 + cq * 4;
        *(uint2*)&xpad[r0] = make_uint2(0u, 0u);
        *(uint2*)&xpad[r1] = make_uint2(0u, 0u);
        if (w0 == 0 && tid < 128) {
            int corner = tid >> 5, cc = tid & 31;
            int hp = (corner & 1) ? 129 : 0;
            int wp = (corner & 2) ? 129 : 0;
            xpad[((size_t)(b * HP_ + hp) * WP_ + wp) * C_ + c0 + cc] = 0;
        }
    }
    if (w0 == 0 && tid < 64) {
        int side = tid >> 5, cc = tid & 31;
        int wp = side ? 129 : 0;
        xpad[((size_t)(b * HP_ + h + 1) * WP_ + wp) * C_ + c0 + cc] = 0;
    }
    __syncthreads();
    // ---- wide store phase: 128 x uint4 (16 B per store, 64 B runs per w) ----
    if (tid < 128) {
        int w = tid >> 2, u4 = tid & 3;
        unsigned r0 = pack_bf2(tile[8 * u4 + 0][w], tile[8 * u4 + 1][w]);
        unsigned r1 = pack_bf2(tile[8 * u4 + 2][w], tile[8 * u4 + 3][w]);
        unsigned r2 = pack_bf2(tile[8 * u4 + 4][w], tile[8 * u4 + 5][w]);
        unsigned r3 = pack_bf2(tile[8 * u4 + 6][w], tile[8 * u4 + 7][w]);
        *(uint4*)&xpad[((size_t)((b * HP_ + h + 1) * WP_ + (w0 + w + 1))) * C_ + c0 + u4 * 8] =
            make_uint4(r0, r1, r2, r3);
    }
}

// ---------------- K2: offset conv as MFMA GEMM (M=18 pad 32, K=1152) ----------------
__global__ __launch_bounds__(256) void k_offconv(const unsigned short* __restrict__ xpad,
                                                 const short* __restrict__ wofff,
                                                 const float* __restrict__ p_b,
                                                 float* __restrict__ offT) {
    int t = threadIdx.x;
    int ph = blockIdx.x;
    int h  = blockIdx.y;
    int b  = blockIdx.z;
    const unsigned short* xb = xpad + (size_t)b * HP_ * WP_ * C_;
    int lane = t & 63, wv = t >> 6;
    int q = lane >> 4, l15 = lane & 15;
    int pos0 = ph * 64 + wv * 16;
    int poscol = pos0 + l15;

    f32x4 accA = {0.f, 0.f, 0.f, 0.f}, accB = {0.f, 0.f, 0.f, 0.f};
    const bf16x8* Wf = (const bf16x8*)wofff;

    for (int tap = 0; tap < 9; tap++) {
        int row = h + tap / 3;
        int col = poscol + tap % 3;
        const unsigned short* src = xb + ((size_t)(row * WP_ + col)) * C_ + q * 8;
#pragma unroll
        for (int kc = 0; kc < 4; kc++) {
            bf16x8 a0 = Wf[(size_t)(((tap * 4 + kc) * 4 + q) * 32) + l15];
            bf16x8 a1 = Wf[(size_t)(((tap * 4 + kc) * 4 + q) * 32) + 16 + l15];
            bf16x8 bv = *(const bf16x8*)(src + kc * 32);
            accA = __builtin_amdgcn_mfma_f32_16x16x32_bf16(a0, bv, accA, 0, 0, 0);
            accB = __builtin_amdgcn_mfma_f32_16x16x32_bf16(a1, bv, accB, 0, 0, 0);
        }
    }
    size_t hw = (size_t)h * W_ + pos0 + l15;
#pragma unroll
    for (int r = 0; r < 4; r++) {
        int j = q * 4 + r;
        offT[((size_t)(b * 18 + j)) * HW_ + hw] = accA[r] + p_b[j];
    }
    if (q == 0) {
#pragma unroll
        for (int r = 0; r < 2; r++) {
            int j = 16 + r;
            offT[((size_t)(b * 18 + j)) * HW_ + hw] = accB[r] + p_b[j];
        }
    }
}

// ---------------- K3: one block per (b,h); R1 proven pipeline (1 barrier/step, implicit sync) ----------------
__global__ __launch_bounds__(512, 4) void k_main(const unsigned short* __restrict__ xpad,
                                                 const float* __restrict__ offT,
                                                 const unsigned short* __restrict__ wrepb,
                                                 float* __restrict__ out,
                                                 float* __restrict__ stats,
                                                 unsigned short* __restrict__ rawout,
                                                 int bf16flag) {
    __shared__ short Wl[2][8192];        // double-buffered W chunk, 32 KB
    __shared__ short Vl[2][4128];        // double-buffered skewed V, 16.1 KB
    __shared__ int   pbase[2][4][128];   // tap-parity double buffer, 4 KB
    __shared__ float pg[2][4][128];      // 4 KB
    __shared__ float red0[256], red1[256];

    int t = threadIdx.x;
    int i_blk = blockIdx.x;
    int b = i_blk & 3;                   // XCD k serves b = k&3 only (round-robin heuristic)
    int h = i_blk >> 2;
    const unsigned short* xb = xpad + (size_t)b * HP_ * WP_ * C_;

    int lane = t & 63, wv = t >> 6;      // 8 waves
    int q = lane >> 4, l15 = lane & 15;
    int m0 = (wv & 3) * 64;              // o-slice
    int ph = wv >> 2;                    // pos half
    int n0 = ph * 64;
    int c4g = t & 3, posb = t >> 2;      // gather: 4 ch-subquads x 128 pos

    auto OFFSETS = [&](int n, int pb) {
        if (t < 128) {
            int w = t;
            float offx = offT[((size_t)(b * 18 + n)) * HW_ + h * W_ + w];
            float offy = offT[((size_t)(b * 18 + 9 + n)) * HW_ + h * W_ + w];
            int dxn = n / 3 - 1, dyn = n % 3 - 1;
            float px = (float)(h + 1 + dxn) + offx;
            float py = (float)(w + 1 + dyn) + offy;
            float pcx = fminf(fmaxf(px, 0.f), 129.f);
            float pcy = fminf(fmaxf(py, 0.f), 129.f);
            float fx = floorf(px), fy = floorf(py);
            float q0x = fminf(fmaxf(fx, 0.f), 129.f);
            float q0y = fminf(fmaxf(fy, 0.f), 129.f);
            float q1x = fminf(fmaxf(fx + 1.f, 0.f), 129.f);
            float q1y = fminf(fmaxf(fy + 1.f, 0.f), 129.f);
            float wx0 = 1.f + (q0x - pcx), wx1 = 1.f - (q1x - pcx);
            float wy0 = 1.f + (q0y - pcy), wy1 = 1.f - (q1y - pcy);
            int i0x = (int)q0x, i0y = (int)q0y, i1x = (int)q1x, i1y = (int)q1y;
            pbase[pb][0][w] = (i0x * WP_ + i0y) * C_;
            pbase[pb][1][w] = (i1x * WP_ + i1y) * C_;
            pbase[pb][2][w] = (i0x * WP_ + i1y) * C_;
            pbase[pb][3][w] = (i1x * WP_ + i0y) * C_;
            pg[pb][0][w] = wx0 * wy0;
            pg[pb][1][w] = wx1 * wy1;
            pg[pb][2][w] = wx0 * wy1;
            pg[pb][3][w] = wx1 * wy0;
        }
    };

    f32x4 acc[4][4];
#pragma unroll
    for (int i = 0; i < 4; i++)
#pragma unroll
        for (int j = 0; j < 4; j++) acc[i][j] = (f32x4){0.f, 0.f, 0.f, 0.f};

    if (t < 256) { red0[t] = 0.f; red1[t] = 0.f; }   // hoisted epilogue init (inert during loop)
    OFFSETS(0, 0);
    __syncthreads();

    // ---- prologue: stage step 0 into buffer 0 ----
    {
        const unsigned short* ws = wrepb;            // chunk 0
        GLD_LDS16(ws + (size_t)t * 8, &Wl[0][wv * 512]);
        GLD_LDS16(ws + (size_t)(t + 512) * 8, &Wl[0][wv * 512 + 4096]);
        int cof = c4g * 8;                           // kc=0
        uint4 A  = *(const uint4*)(xb + pbase[0][0][posb] + cof);
        uint4 Bv = *(const uint4*)(xb + pbase[0][1][posb] + cof);
        uint4 Cv = *(const uint4*)(xb + pbase[0][2][posb] + cof);
        uint4 Dv = *(const uint4*)(xb + pbase[0][3][posb] + cof);
        float g0 = pg[0][0][posb], g1 = pg[0][1][posb], g2 = pg[0][2][posb], g3 = pg[0][3][posb];
        unsigned outw[4];
#pragma unroll
        for (int k = 0; k < 4; k++) {
            unsigned ua = (&A.x)[k], ub = (&Bv.x)[k], uc = (&Cv.x)[k], ud = (&Dv.x)[k];
            float alo = __builtin_bit_cast(float, ua << 16), ahi = __builtin_bit_cast(float, ua & 0xffff0000u);
            float blo = __builtin_bit_cast(float, ub << 16), bhi = __builtin_bit_cast(float, ub & 0xffff0000u);
            float clo = __builtin_bit_cast(float, uc << 16), chi = __builtin_bit_cast(float, uc & 0xffff0000u);
            float dlo = __builtin_bit_cast(float, ud << 16), dhi = __builtin_bit_cast(float, ud & 0xffff0000u);
            float vlo = g0 * alo + g1 * blo + g2 * clo + g3 * dlo;
            float vhi = g0 * ahi + g1 * bhi + g2 * chi + g3 * dhi;
            outw[k] = pack_bf2(vlo, vhi);
        }
        *(uint4*)&Vl[0][(unsigned)(c4g * 129 + posb) * 8] = make_uint4(outw[0], outw[1], outw[2], outw[3]);
    }
    __syncthreads();

    // ---- main pipelined loop: 36 steps, 1 barrier per step (R1 proven structure) ----
#pragma unroll 1
    for (int s = 0; s < 36; s++) {
        int cur = s & 1, nxt = cur ^ 1;
        uint4 A, Bv, Cv, Dv;
        float g0 = 0.f, g1 = 0.f, g2 = 0.f, g3 = 0.f;
        bool st = (s < 35);
        if (st) {
            int s1 = s + 1;
            const unsigned short* ws = wrepb + (size_t)s1 * 8192;
            GLD_LDS16(ws + (size_t)t * 8, &Wl[nxt][wv * 512]);
            GLD_LDS16(ws + (size_t)(t + 512) * 8, &Wl[nxt][wv * 512 + 4096]);
            int n1 = s1 >> 2, kc1 = s1 & 3, pb1 = n1 & 1;
            int cof = kc1 * 32 + c4g * 8;
            A  = *(const uint4*)(xb + pbase[pb1][0][posb] + cof);
            Bv = *(const uint4*)(xb + pbase[pb1][1][posb] + cof);
            Cv = *(const uint4*)(xb + pbase[pb1][2][posb] + cof);
            Dv = *(const uint4*)(xb + pbase[pb1][3][posb] + cof);
            g0 = pg[pb1][0][posb]; g1 = pg[pb1][1][posb];
            g2 = pg[pb1][2][posb]; g3 = pg[pb1][3][posb];
        }
        // consume step s: loads for s+1 are in flight underneath the MFMAs
        {
            const bf16x8* Af = (const bf16x8*)Wl[cur];
            const bf16x8* Bf = (const bf16x8*)Vl[cur];
            bf16x8 av[4];
#pragma unroll
            for (int i = 0; i < 4; i++) av[i] = Af[q * 256 + m0 + i * 16 + l15];
            __builtin_amdgcn_s_setprio(1);
#pragma unroll
            for (int j = 0; j < 4; j++) {
                bf16x8 bv = Bf[q * 129 + n0 + j * 16 + l15];
#pragma unroll
                for (int i = 0; i < 4; i++)
                    acc[i][j] = __builtin_amdgcn_mfma_f32_16x16x32_bf16(av[i], bv, acc[i][j], 0, 0, 0);
            }
            __builtin_amdgcn_s_setprio(0);
        }
        // compute offsets one tap ahead (off the critical path, disjoint pb buffer)
        if ((s & 3) == 2) {
            int n = s >> 2;
            if (n < 8) OFFSETS(n + 1, (n + 1) & 1);
        }
        if (st) {
            unsigned outw[4];
#pragma unroll
            for (int k = 0; k < 4; k++) {
                unsigned ua = (&A.x)[k], ub = (&Bv.x)[k], uc = (&Cv.x)[k], ud = (&Dv.x)[k];
                float alo = __builtin_bit_cast(float, ua << 16), ahi = __builtin_bit_cast(float, ua & 0xffff0000u);
                float blo = __builtin_bit_cast(float, ub << 16), bhi = __builtin_bit_cast(float, ub & 0xffff0000u);
                float clo = __builtin_bit_cast(float, uc << 16), chi = __builtin_bit_cast(float, uc & 0xffff0000u);
                float dlo = __builtin_bit_cast(float, ud << 16), dhi = __builtin_bit_cast(float, ud & 0xffff0000u);
                float vlo = g0 * alo + g1 * blo + g2 * clo + g3 * dlo;
                float vhi = g0 * ahi + g1 * bhi + g2 * chi + g3 * dhi;
                outw[k] = pack_bf2(vlo, vhi);
            }
            *(uint4*)&Vl[nxt][(unsigned)(c4g * 129 + posb) * 8] = make_uint4(outw[0], outw[1], outw[2], outw[3]);
        }
        __syncthreads();
    }

    // ---- epilogue: BN partial sums ----
#pragma unroll
    for (int i = 0; i < 4; i++) {
#pragma unroll
        for (int r = 0; r < 4; r++) {
            int o_loc = m0 + i * 16 + q * 4 + r;
            float s = 0.f, s2 = 0.f;
#pragma unroll
            for (int j = 0; j < 4; j++) { float v = acc[i][j][r]; s += v; s2 += v * v; }
            s  += __shfl_xor(s, 1);  s  += __shfl_xor(s, 2);  s  += __shfl_xor(s, 4);  s  += __shfl_xor(s, 8);
            s2 += __shfl_xor(s2, 1); s2 += __shfl_xor(s2, 2); s2 += __shfl_xor(s2, 4); s2 += __shfl_xor(s2, 8);
            if (l15 == 0) { atomicAdd(&red0[o_loc], s); atomicAdd(&red1[o_loc], s2); }
        }
    }
    __syncthreads();
    if (t < 256) {
        atomicAdd(&stats[t], red0[t]);
        atomicAdd(&stats[256 + t], red1[t]);
    }

    // ---- epilogue: raw C write (bf16 to ws if it fits, else fp32 direct) ----
    if (bf16flag) {
        unsigned short* rb = rawout + ((size_t)b * O_) * HW_ + (size_t)h * W_;
#pragma unroll
        for (int i = 0; i < 4; i++)
#pragma unroll
            for (int j = 0; j < 4; j++) {
                int col = ph * 64 + j * 16 + l15;
#pragma unroll
                for (int r = 0; r < 4; r++) {
                    int o = m0 + i * 16 + q * 4 + r;
                    rb[(size_t)o * HW_ + col] = bf16_rne(acc[i][j][r]);
                }
            }
    } else {
        float* outb = out + ((size_t)b * O_) * HW_ + (size_t)h * W_;
#pragma unroll
        for (int i = 0; i < 4; i++)
#pragma unroll
            for (int j = 0; j < 4; j++) {
                int col = ph * 64 + j * 16 + l15;
#pragma unroll
                for (int r = 0; r < 4; r++) {
                    int o = m0 + i * 16 + q * 4 + r;
                    outb[(size_t)o * HW_ + col] = acc[i][j][r];
                }
            }
    }
}

// ---------------- K5a: BN finalize + normalize + leaky ReLU from bf16 raw ----------------
__global__ __launch_bounds__(256) void k_apply_bf16(const unsigned short* __restrict__ raw,
                                                    float* __restrict__ out,
                                                    const float* __restrict__ stats,
                                                    const float* __restrict__ gamma,
                                                    const float* __restrict__ beta) {
    size_t idx = (size_t)blockIdx.x * 256 + threadIdx.x;
    size_t e = idx * 8;
    int o = (int)((e >> 14) & 255);      // uniform per 8-elem group
    float s0 = stats[o], s2v = stats[256 + o];
    float mean = s0 * (1.f / 65536.f);
    float var = s2v * (1.f / 65536.f) - mean * mean;
    float sc = gamma[o] * rsqrtf(var + 1e-5f);
    float sh = beta[o] - mean * sc;
    uint4 rv = *(const uint4*)(raw + e);
    float vo[8];
#pragma unroll
    for (int k = 0; k < 4; k++) {
        unsigned w = (&rv.x)[k];
        vo[2 * k]     = __builtin_bit_cast(float, w << 16);
        vo[2 * k + 1] = __builtin_bit_cast(float, w & 0xffff0000u);
    }
#pragma unroll
    for (int k = 0; k < 8; k++) {
        float v = vo[k] * sc + sh;
        vo[k] = (v >= 0.f) ? v : 0.1f * v;
    }
    *(float4*)(out + e)     = make_float4(vo[0], vo[1], vo[2], vo[3]);
    *(float4*)(out + e + 4) = make_float4(vo[4], vo[5], vo[6], vo[7]);
}

// ---------------- K5b: fallback — BN finalize + normalize + leaky ReLU in-place fp32 ----------------
__global__ __launch_bounds__(256) void k_apply_f32(float* __restrict__ out,
                                                   const float* __restrict__ stats,
                                                   const float* __restrict__ gamma,
                                                   const float* __restrict__ beta) {
    int idx = blockIdx.x * 256 + threadIdx.x;
    int e = idx * 4;
    int o = (e >> 14) & 255;
    float s0 = stats[o], s2v = stats[256 + o];
    float mean = s0 * (1.f / 65536.f);
    float var = s2v * (1.f / 65536.f) - mean * mean;
    float sc = gamma[o] * rsqrtf(var + 1e-5f);
    float sh = beta[o] - mean * sc;
    float4 v = *(float4*)(out + e);
    v.x = v.x * sc + sh; v.x = (v.x >= 0.f) ? v.x : 0.1f * v.x;
    v.y = v.y * sc + sh; v.y = (v.y >= 0.f) ? v.y : 0.1f * v.y;
    v.z = v.z * sc + sh; v.z = (v.z >= 0.f) ? v.z : 0.1f * v.z;
    v.w = v.w * sc + sh; v.w = (v.w >= 0.f) ? v.w : 0.1f * v.w;
    *(float4*)(out + e) = v;
}

extern "C" void kernel_launch(void* const* d_in, const int* in_sizes, int n_in,
                              void* d_out, int out_size, void* d_ws, size_t ws_size,
                              hipStream_t stream) {
    const float* x      = (const float*)d_in[0];
    const float* p_w    = (const float*)d_in[1];
    const float* p_b    = (const float*)d_in[2];
    const float* w_conv = (const float*)d_in[3];
    const float* gamma  = (const float*)d_in[4];
    const float* beta   = (const float*)d_in[5];
    float* out = (float*)d_out;

    char* wsb = (char*)d_ws;
    unsigned short* xpad  = (unsigned short*)wsb;
    float*          offT  = (float*)(wsb + OFF_BYTE);
    unsigned short* wrepb = (unsigned short*)(wsb + WREPB_BYTE);
    float*          stats = (float*)(wsb + STATS_BYTE);
    short*          wofff = (short*)(wsb + WOFF_BYTE);
    unsigned short* rawo  = (unsigned short*)(wsb + RAW_BYTE);

    int bf16flag = (ws_size >= WS_NEED) ? 1 : 0;

    k_transpose<<<dim3(W_ / 32, C_ / 32, B_ * H_), dim3(32, 8), 0, stream>>>(
        x, xpad, p_w, wofff, w_conv, wrepb, stats);
    k_offconv<<<dim3(2, H_, B_), 256, 0, stream>>>(xpad, wofff, p_b, offT);
    k_main<<<dim3(512), 512, 0, stream>>>(xpad, offT, wrepb, out, stats, rawo, bf16flag);
    if (bf16flag)
        k_apply_bf16<<<dim3(B_ * O_ * HW_ / (256 * 8)), 256, 0, stream>>>(rawo, out, stats, gamma, beta);
    else
        k_apply_f32<<<dim3(B_ * O_ * HW_ / (256 * 4)), 256, 0, stream>>>(out, stats, gamma, beta);
}

// Round 8
// 211.009 us; speedup vs baseline: 1.1914x; 1.0185x over previous
//
#include <hip/hip_runtime.h>
#include <hip/hip_fp16.h>
#include <cstdint>

typedef __attribute__((ext_vector_type(8))) short bf16x8;
typedef __attribute__((ext_vector_type(4))) float f32x4;

#define B_   4
#define C_   128
#define H_   128
#define W_   128
#define HP_  130
#define WP_  130
#define O_   256
#define HW_  (H_*W_)          // 16384

// ws layout (byte offsets)
#define XPAD_BYTES   (B_*HP_*WP_*C_*2)          // bf16 xpad: 17,305,600
#define WREPB_BYTE   XPAD_BYTES
#define WREPB_BYTES  (9*C_*O_*2)                // 589,824
#define STATS_BYTE   (WREPB_BYTE + WREPB_BYTES)
#define WOFF_BYTE    (STATS_BYTE + 4096)
#define WOFF_BYTES   (9*4*4*32*8*2)             // 73,728
#define RAW_BYTE     ((WOFF_BYTE + WOFF_BYTES + 255) & ~255)
#define RAW_BYTES    ((size_t)B_*O_*HW_*2)      // 33,554,432 bf16 raw out
#define WS_NEED      ((size_t)RAW_BYTE + RAW_BYTES)

typedef __attribute__((address_space(1))) const void gconst_void;
typedef __attribute__((address_space(3))) void lds_void;
#define GLD_LDS16(gp, lp) __builtin_amdgcn_global_load_lds((gconst_void*)(gp), (lds_void*)(lp), 16, 0, 0)

__device__ __forceinline__ unsigned pack_bf2(float a, float b) {
    unsigned ua = __builtin_bit_cast(unsigned, a) + 0x8000u;
    unsigned ub = __builtin_bit_cast(unsigned, b) + 0x8000u;
    return __builtin_amdgcn_perm(ub, ua, 0x07060302u);
}

__device__ __forceinline__ unsigned short bf16_rne(float f) {
    unsigned u = __builtin_bit_cast(unsigned, f);
    u += 0x7fffu + ((u >> 16) & 1u);
    return (unsigned short)(u >> 16);
}

// ---------------- K1: NCHW fp32 -> padded NHWC bf16 transpose + ring zeroing + fused repack ----------------
__global__ void k_transpose(const float* __restrict__ x, unsigned short* __restrict__ xpad,
                            const float* __restrict__ p_w, short* __restrict__ wofff,
                            const float* __restrict__ w_conv, unsigned short* __restrict__ wrepb,
                            float* __restrict__ stats) {
    __shared__ float tile[32][33];   // [c_loc][w_loc]
    int w0 = blockIdx.x * 32, c0 = blockIdx.y * 32;
    int bh = blockIdx.z;
    int b = bh >> 7, h = bh & 127;
    int tx = threadIdx.x, ty = threadIdx.y;
#pragma unroll
    for (int i = 0; i < 4; i++) {
        int c = c0 + ty + i * 8;
        tile[ty + i * 8][tx] = x[((b * C_ + c) * H_ + h) * W_ + w0 + tx];
    }
    int tid = ty * 32 + tx;
    // ---- fused repack (first 1296 flat blocks): p_w->wofff, w_conv->wrepb, stats zero ----
    {
        int fb = (bh * 4 + (int)blockIdx.y) * 4 + (int)blockIdx.x;
        int i = fb * 256 + tid;
        if (i < 1024) stats[i] = 0.f;
        if (i < 9 * 4096) {
            int e = i & 7, m = (i >> 3) & 31, q = (i >> 8) & 3, kc = (i >> 10) & 3, tap = i >> 12;
            float f = (m < 18) ? p_w[((size_t)m * C_ + kc * 32 + q * 8 + e) * 9 + tap] : 0.f;
            wofff[i] = (short)bf16_rne(f);
        }
        int j = i - 9 * 4096;
        if (j >= 0 && j < 9 * C_ * O_) {
            int ki8 = j & 7;
            int o   = (j >> 3) & 255;
            int kq  = (j >> 11) & 3;
            int kc  = (j >> 13) & 3;
            int n   = j >> 15;
            int c = kc * 32 + kq * 8 + ki8;
            wrepb[j] = bf16_rne(w_conv[(o * C_ + c) * 9 + n]);
        }
    }
    // ---- padding-ring zeroing (interior is fully overwritten) ----
    if (h == 0) {
        int wloc = tid >> 3, cq = tid & 7;
        size_t r0 = ((size_t)(b * HP_ + 0)   * WP_ + (w0 + 1 + wloc)) * C_ + c0 + cq * 4;
        size_t r1 = ((size_t)(b * HP_ + 129) * WP_ + (w0 + 1 + wloc)) * C_ + c0 + cq * 4;
        *(uint2*)&xpad[r0] = make_uint2(0u, 0u);
        *(uint2*)&xpad[r1] = make_uint2(0u, 0u);
        if (w0 == 0 && tid < 128) {
            int corner = tid >> 5, cc = tid & 31;
            int hp = (corner & 1) ? 129 : 0;
            int wp = (corner & 2) ? 129 : 0;
            xpad[((size_t)(b * HP_ + hp) * WP_ + wp) * C_ + c0 + cc] = 0;
        }
    }
    if (w0 == 0 && tid < 64) {
        int side = tid >> 5, cc = tid & 31;
        int wp = side ? 129 : 0;
        xpad[((size_t)(b * HP_ + h + 1) * WP_ + wp) * C_ + c0 + cc] = 0;
    }
    __syncthreads();
    // ---- wide store phase: 128 x uint4 (16 B per store, 64 B runs per w) ----
    if (tid < 128) {
        int w = tid >> 2, u4 = tid & 3;
        unsigned r0 = pack_bf2(tile[8 * u4 + 0][w], tile[8 * u4 + 1][w]);
        unsigned r1 = pack_bf2(tile[8 * u4 + 2][w], tile[8 * u4 + 3][w]);
        unsigned r2 = pack_bf2(tile[8 * u4 + 4][w], tile[8 * u4 + 5][w]);
        unsigned r3 = pack_bf2(tile[8 * u4 + 6][w], tile[8 * u4 + 7][w]);
        *(uint4*)&xpad[((size_t)((b * HP_ + h + 1) * WP_ + (w0 + w + 1))) * C_ + c0 + u4 * 8] =
            make_uint4(r0, r1, r2, r3);
    }
}

// ---------------- K3: one block per (b,h); fused offset-conv prologue + R1 pipeline ----------------
__global__ __launch_bounds__(512, 4) void k_main(const unsigned short* __restrict__ xpad,
                                                 const short* __restrict__ wofff,
                                                 const float* __restrict__ p_b,
                                                 const unsigned short* __restrict__ wrepb,
                                                 float* __restrict__ out,
                                                 float* __restrict__ stats,
                                                 unsigned short* __restrict__ rawout,
                                                 int bf16flag) {
    __shared__ short Wl[2][8192];        // double-buffered W chunk, 32 KB (offset bounce in prologue)
    __shared__ short Vl[2][4128];        // double-buffered skewed V, 16.1 KB (red0/1 aliased after loop)
    __shared__ unsigned pbaseP[9][128];  // packed u8x4 corner coords, 4.5 KB
    __shared__ unsigned pg01[9][128];    // half2(g0,g1), 4.5 KB
    __shared__ unsigned pg23[9][128];    // half2(g2,g3), 4.5 KB

    int t = threadIdx.x;
    int i_blk = blockIdx.x;
    int b = i_blk & 3;
    int h = i_blk >> 2;
    const unsigned short* xb = xpad + (size_t)b * HP_ * WP_ * C_;

    int lane = t & 63, wv = t >> 6;      // 8 waves
    int q = lane >> 4, l15 = lane & 15;
    int m0 = (wv & 3) * 64;              // o-slice
    int ph = wv >> 2;                    // pos half
    int n0 = ph * 64;
    int c4g = t & 3, posb = t >> 2;      // gather: 4 ch-subquads x 128 pos

    // ================= PROLOGUE A: offset conv for this (b,h) =================
    {
        float* off_lds = (float*)&Wl[0][0];          // [18][128] = 9 KB, Wl free here
        f32x4 accA = {0.f, 0.f, 0.f, 0.f}, accB = {0.f, 0.f, 0.f, 0.f};
        const bf16x8* Wf = (const bf16x8*)wofff;
        int poscol = wv * 16 + l15;                  // this lane's position 0..127
        for (int tap = 0; tap < 9; tap++) {
            int row = h + tap / 3;
            int col = poscol + tap % 3;
            const unsigned short* src = xb + ((size_t)(row * WP_ + col)) * C_ + q * 8;
#pragma unroll
            for (int kc = 0; kc < 4; kc++) {
                bf16x8 a0 = Wf[(size_t)(((tap * 4 + kc) * 4 + q) * 32) + l15];
                bf16x8 a1 = Wf[(size_t)(((tap * 4 + kc) * 4 + q) * 32) + 16 + l15];
                bf16x8 bv = *(const bf16x8*)(src + kc * 32);
                accA = __builtin_amdgcn_mfma_f32_16x16x32_bf16(a0, bv, accA, 0, 0, 0);
                accB = __builtin_amdgcn_mfma_f32_16x16x32_bf16(a1, bv, accB, 0, 0, 0);
            }
        }
#pragma unroll
        for (int r = 0; r < 4; r++) {
            int j = q * 4 + r;
            off_lds[j * 128 + poscol] = accA[r] + p_b[j];
        }
        if (q == 0) {
#pragma unroll
            for (int r = 0; r < 2; r++) {
                int j = 16 + r;
                off_lds[j * 128 + poscol] = accB[r] + p_b[j];
            }
        }
    }
    __syncthreads();
    // ================= PROLOGUE B: offsets -> packed bilinear tables =================
    if (t < 128) {
        const float* off_lds = (const float*)&Wl[0][0];
        int w = t;
#pragma unroll
        for (int n = 0; n < 9; n++) {
            float offx = off_lds[n * 128 + w];
            float offy = off_lds[(9 + n) * 128 + w];
            float px = (float)(h + n / 3) + offx;        // h+1+(n/3-1)
            float py = (float)(w + n % 3) + offy;        // w+1+(n%3-1)
            float pcx = fminf(fmaxf(px, 0.f), 129.f);
            float pcy = fminf(fmaxf(py, 0.f), 129.f);
            float fx = floorf(px), fy = floorf(py);
            float q0x = fminf(fmaxf(fx, 0.f), 129.f);
            float q0y = fminf(fmaxf(fy, 0.f), 129.f);
            float q1x = fminf(fmaxf(fx + 1.f, 0.f), 129.f);
            float q1y = fminf(fmaxf(fy + 1.f, 0.f), 129.f);
            float wx0 = 1.f + (q0x - pcx), wx1 = 1.f - (q1x - pcx);
            float wy0 = 1.f + (q0y - pcy), wy1 = 1.f - (q1y - pcy);
            unsigned i0x = (unsigned)q0x, i0y = (unsigned)q0y;
            unsigned i1x = (unsigned)q1x, i1y = (unsigned)q1y;
            pbaseP[n][w] = i0x | (i0y << 8) | (i1x << 16) | (i1y << 24);
            __half2 h01 = __floats2half2_rn(wx0 * wy0, wx1 * wy1);
            __half2 h23 = __floats2half2_rn(wx0 * wy1, wx1 * wy0);
            pg01[n][w] = __builtin_bit_cast(unsigned, h01);
            pg23[n][w] = __builtin_bit_cast(unsigned, h23);
        }
    }
    __syncthreads();

    // gather helper: unpack packed tables -> 4 corner bases + 4 weights
    auto UNPACK = [&](int n, int& b0, int& b1, int& b2, int& b3,
                      float& g0, float& g1, float& g2, float& g3) {
        unsigned bp = pbaseP[n][posb];
        int t0 = (int)(bp & 255u) * WP_;
        int y0 = (int)((bp >> 8) & 255u);
        int t1 = (int)((bp >> 16) & 255u) * WP_;
        int y1 = (int)(bp >> 24);
        b0 = (t0 + y0) * C_; b1 = (t1 + y1) * C_;
        b2 = (t0 + y1) * C_; b3 = (t1 + y0) * C_;
        __half2 h01 = __builtin_bit_cast(__half2, pg01[n][posb]);
        __half2 h23 = __builtin_bit_cast(__half2, pg23[n][posb]);
        g0 = __low2float(h01); g1 = __high2float(h01);
        g2 = __low2float(h23); g3 = __high2float(h23);
    };

    f32x4 acc[4][4];
#pragma unroll
    for (int i = 0; i < 4; i++)
#pragma unroll
        for (int j = 0; j < 4; j++) acc[i][j] = (f32x4){0.f, 0.f, 0.f, 0.f};

    // ---- prologue C: stage step 0 into buffer 0 ----
    {
        const unsigned short* ws = wrepb;            // chunk 0
        GLD_LDS16(ws + (size_t)t * 8, &Wl[0][wv * 512]);
        GLD_LDS16(ws + (size_t)(t + 512) * 8, &Wl[0][wv * 512 + 4096]);
        int b0, b1, b2, b3; float g0, g1, g2, g3;
        UNPACK(0, b0, b1, b2, b3, g0, g1, g2, g3);
        int cof = c4g * 8;                           // kc=0
        uint4 A  = *(const uint4*)(xb + b0 + cof);
        uint4 Bv = *(const uint4*)(xb + b1 + cof);
        uint4 Cv = *(const uint4*)(xb + b2 + cof);
        uint4 Dv = *(const uint4*)(xb + b3 + cof);
        unsigned outw[4];
#pragma unroll
        for (int k = 0; k < 4; k++) {
            unsigned ua = (&A.x)[k], ub = (&Bv.x)[k], uc = (&Cv.x)[k], ud = (&Dv.x)[k];
            float alo = __builtin_bit_cast(float, ua << 16), ahi = __builtin_bit_cast(float, ua & 0xffff0000u);
            float blo = __builtin_bit_cast(float, ub << 16), bhi = __builtin_bit_cast(float, ub & 0xffff0000u);
            float clo = __builtin_bit_cast(float, uc << 16), chi = __builtin_bit_cast(float, uc & 0xffff0000u);
            float dlo = __builtin_bit_cast(float, ud << 16), dhi = __builtin_bit_cast(float, ud & 0xffff0000u);
            float vlo = g0 * alo + g1 * blo + g2 * clo + g3 * dlo;
            float vhi = g0 * ahi + g1 * bhi + g2 * chi + g3 * dhi;
            outw[k] = pack_bf2(vlo, vhi);
        }
        *(uint4*)&Vl[0][(unsigned)(c4g * 129 + posb) * 8] = make_uint4(outw[0], outw[1], outw[2], outw[3]);
    }
    __syncthreads();

    // ---- main pipelined loop: 36 steps, 1 barrier per step (R1 proven structure) ----
#pragma unroll 1
    for (int s = 0; s < 36; s++) {
        int cur = s & 1, nxt = cur ^ 1;
        uint4 A, Bv, Cv, Dv;
        float g0 = 0.f, g1 = 0.f, g2 = 0.f, g3 = 0.f;
        bool st = (s < 35);
        if (st) {
            int s1 = s + 1;
            const unsigned short* ws = wrepb + (size_t)s1 * 8192;
            GLD_LDS16(ws + (size_t)t * 8, &Wl[nxt][wv * 512]);
            GLD_LDS16(ws + (size_t)(t + 512) * 8, &Wl[nxt][wv * 512 + 4096]);
            int n1 = s1 >> 2, kc1 = s1 & 3;
            int b0, b1, b2, b3;
            UNPACK(n1, b0, b1, b2, b3, g0, g1, g2, g3);
            int cof = kc1 * 32 + c4g * 8;
            A  = *(const uint4*)(xb + b0 + cof);
            Bv = *(const uint4*)(xb + b1 + cof);
            Cv = *(const uint4*)(xb + b2 + cof);
            Dv = *(const uint4*)(xb + b3 + cof);
        }
        // consume step s: loads for s+1 are in flight underneath the MFMAs
        {
            const bf16x8* Af = (const bf16x8*)Wl[cur];
            const bf16x8* Bf = (const bf16x8*)Vl[cur];
            bf16x8 av[4];
#pragma unroll
            for (int i = 0; i < 4; i++) av[i] = Af[q * 256 + m0 + i * 16 + l15];
            __builtin_amdgcn_s_setprio(1);
#pragma unroll
            for (int j = 0; j < 4; j++) {
                bf16x8 bv = Bf[q * 129 + n0 + j * 16 + l15];
#pragma unroll
                for (int i = 0; i < 4; i++)
                    acc[i][j] = __builtin_amdgcn_mfma_f32_16x16x32_bf16(av[i], bv, acc[i][j], 0, 0, 0);
            }
            __builtin_amdgcn_s_setprio(0);
        }
        if (st) {
            unsigned outw[4];
#pragma unroll
            for (int k = 0; k < 4; k++) {
                unsigned ua = (&A.x)[k], ub = (&Bv.x)[k], uc = (&Cv.x)[k], ud = (&Dv.x)[k];
                float alo = __builtin_bit_cast(float, ua << 16), ahi = __builtin_bit_cast(float, ua & 0xffff0000u);
                float blo = __builtin_bit_cast(float, ub << 16), bhi = __builtin_bit_cast(float, ub & 0xffff0000u);
                float clo = __builtin_bit_cast(float, uc << 16), chi = __builtin_bit_cast(float, uc & 0xffff0000u);
                float dlo = __builtin_bit_cast(float, ud << 16), dhi = __builtin_bit_cast(float, ud & 0xffff0000u);
                float vlo = g0 * alo + g1 * blo + g2 * clo + g3 * dlo;
                float vhi = g0 * ahi + g1 * bhi + g2 * chi + g3 * dhi;
                outw[k] = pack_bf2(vlo, vhi);
            }
            *(uint4*)&Vl[nxt][(unsigned)(c4g * 129 + posb) * 8] = make_uint4(outw[0], outw[1], outw[2], outw[3]);
        }
        __syncthreads();
    }

    // ---- epilogue: BN partial sums (red0/red1 aliased onto dead Vl) ----
    float* red0 = (float*)&Vl[0][0];
    float* red1 = red0 + 256;
    if (t < 256) { red0[t] = 0.f; red1[t] = 0.f; }
    __syncthreads();
#pragma unroll
    for (int i = 0; i < 4; i++) {
#pragma unroll
        for (int r = 0; r < 4; r++) {
            int o_loc = m0 + i * 16 + q * 4 + r;
            float s = 0.f, s2 = 0.f;
#pragma unroll
            for (int j = 0; j < 4; j++) { float v = acc[i][j][r]; s += v; s2 += v * v; }
            s  += __shfl_xor(s, 1);  s  += __shfl_xor(s, 2);  s  += __shfl_xor(s, 4);  s  += __shfl_xor(s, 8);
            s2 += __shfl_xor(s2, 1); s2 += __shfl_xor(s2, 2); s2 += __shfl_xor(s2, 4); s2 += __shfl_xor(s2, 8);
            if (l15 == 0) { atomicAdd(&red0[o_loc], s); atomicAdd(&red1[o_loc], s2); }
        }
    }
    __syncthreads();
    if (t < 256) {
        atomicAdd(&stats[t], red0[t]);
        atomicAdd(&stats[256 + t], red1[t]);
    }

    // ---- epilogue: raw C write (bf16 to ws if it fits, else fp32 direct) ----
    if (bf16flag) {
        unsigned short* rb = rawout + ((size_t)b * O_) * HW_ + (size_t)h * W_;
#pragma unroll
        for (int i = 0; i < 4; i++)
#pragma unroll
            for (int j = 0; j < 4; j++) {
                int col = ph * 64 + j * 16 + l15;
#pragma unroll
                for (int r = 0; r < 4; r++) {
                    int o = m0 + i * 16 + q * 4 + r;
                    rb[(size_t)o * HW_ + col] = bf16_rne(acc[i][j][r]);
                }
            }
    } else {
        float* outb = out + ((size_t)b * O_) * HW_ + (size_t)h * W_;
#pragma unroll
        for (int i = 0; i < 4; i++)
#pragma unroll
            for (int j = 0; j < 4; j++) {
                int col = ph * 64 + j * 16 + l15;
#pragma unroll
                for (int r = 0; r < 4; r++) {
                    int o = m0 + i * 16 + q * 4 + r;
                    outb[(size_t)o * HW_ + col] = acc[i][j][r];
                }
            }
    }
}

// ---------------- K5a: BN finalize + normalize + leaky ReLU from bf16 raw ----------------
__global__ __launch_bounds__(256) void k_apply_bf16(const unsigned short* __restrict__ raw,
                                                    float* __restrict__ out,
                                                    const float* __restrict__ stats,
                                                    const float* __restrict__ gamma,
                                                    const float* __restrict__ beta) {
    size_t idx = (size_t)blockIdx.x * 256 + threadIdx.x;
    size_t e = idx * 8;
    int o = (int)((e >> 14) & 255);      // uniform per 8-elem group
    float s0 = stats[o], s2v = stats[256 + o];
    float mean = s0 * (1.f / 65536.f);
    float var = s2v * (1.f / 65536.f) - mean * mean;
    float sc = gamma[o] * rsqrtf(var + 1e-5f);
    float sh = beta[o] - mean * sc;
    uint4 rv = *(const uint4*)(raw + e);
    float vo[8];
#pragma unroll
    for (int k = 0; k < 4; k++) {
        unsigned w = (&rv.x)[k];
        vo[2 * k]     = __builtin_bit_cast(float, w << 16);
        vo[2 * k + 1] = __builtin_bit_cast(float, w & 0xffff0000u);
    }
#pragma unroll
    for (int k = 0; k < 8; k++) {
        float v = vo[k] * sc + sh;
        vo[k] = (v >= 0.f) ? v : 0.1f * v;
    }
    *(float4*)(out + e)     = make_float4(vo[0], vo[1], vo[2], vo[3]);
    *(float4*)(out + e + 4) = make_float4(vo[4], vo[5], vo[6], vo[7]);
}

// ---------------- K5b: fallback — BN finalize + normalize + leaky ReLU in-place fp32 ----------------
__global__ __launch_bounds__(256) void k_apply_f32(float* __restrict__ out,
                                                   const float* __restrict__ stats,
                                                   const float* __restrict__ gamma,
                                                   const float* __restrict__ beta) {
    int idx = blockIdx.x * 256 + threadIdx.x;
    int e = idx * 4;
    int o = (e >> 14) & 255;
    float s0 = stats[o], s2v = stats[256 + o];
    float mean = s0 * (1.f / 65536.f);
    float var = s2v * (1.f / 65536.f) - mean * mean;
    float sc = gamma[o] * rsqrtf(var + 1e-5f);
    float sh = beta[o] - mean * sc;
    float4 v = *(float4*)(out + e);
    v.x = v.x * sc + sh; v.x = (v.x >= 0.f) ? v.x : 0.1f * v.x;
    v.y = v.y * sc + sh; v.y = (v.y >= 0.f) ? v.y : 0.1f * v.y;
    v.z = v.z * sc + sh; v.z = (v.z >= 0.f) ? v.z : 0.1f * v.z;
    v.w = v.w * sc + sh; v.w = (v.w >= 0.f) ? v.w : 0.1f * v.w;
    *(float4*)(out + e) = v;
}

extern "C" void kernel_launch(void* const* d_in, const int* in_sizes, int n_in,
                              void* d_out, int out_size, void* d_ws, size_t ws_size,
                              hipStream_t stream) {
    const float* x      = (const float*)d_in[0];
    const float* p_w    = (const float*)d_in[1];
    const float* p_b    = (const float*)d_in[2];
    const float* w_conv = (const float*)d_in[3];
    const float* gamma  = (const float*)d_in[4];
    const float* beta   = (const float*)d_in[5];
    float* out = (float*)d_out;

    char* wsb = (char*)d_ws;
    unsigned short* xpad  = (unsigned short*)wsb;
    unsigned short* wrepb = (unsigned short*)(wsb + WREPB_BYTE);
    float*          stats = (float*)(wsb + STATS_BYTE);
    short*          wofff = (short*)(wsb + WOFF_BYTE);
    unsigned short* rawo  = (unsigned short*)(wsb + RAW_BYTE);

    int bf16flag = (ws_size >= WS_NEED) ? 1 : 0;

    k_transpose<<<dim3(W_ / 32, C_ / 32, B_ * H_), dim3(32, 8), 0, stream>>>(
        x, xpad, p_w, wofff, w_conv, wrepb, stats);
    k_main<<<dim3(512), 512, 0, stream>>>(xpad, wofff, p_b, wrepb, out, stats, rawo, bf16flag);
    if (bf16flag)
        k_apply_bf16<<<dim3(B_ * O_ * HW_ / (256 * 8)), 256, 0, stream>>>(rawo, out, stats, gamma, beta);
    else
        k_apply_f32<<<dim3(B_ * O_ * HW_ / (256 * 4)), 256, 0, stream>>>(out, stats, gamma, beta);
}

// Round 9
// 210.626 us; speedup vs baseline: 1.1935x; 1.0018x over previous
//
#include <hip/hip_runtime.h>
#include <hip/hip_fp16.h>
#include <cstdint>

typedef __attribute__((ext_vector_type(8))) short bf16x8;
typedef __attribute__((ext_vector_type(4))) float f32x4;

#define B_   4
#define C_   128
#define H_   128
#define W_   128
#define HP_  130
#define WP_  130
#define O_   256
#define HW_  (H_*W_)          // 16384

// ws layout (byte offsets)
#define XPAD_BYTES   (B_*HP_*WP_*C_*2)          // bf16 xpad: 17,305,600
#define WREPB_BYTE   XPAD_BYTES
#define WREPB_BYTES  (9*C_*O_*2)                // 589,824
#define STATS_BYTE   (WREPB_BYTE + WREPB_BYTES)
#define WOFF_BYTE    (STATS_BYTE + 4096)
#define WOFF_BYTES   (9*4*4*32*8*2)             // 73,728
#define RAW_BYTE     ((WOFF_BYTE + WOFF_BYTES + 255) & ~255)
#define RAW_BYTES    ((size_t)B_*O_*HW_*2)      // 33,554,432 bf16 raw out
#define WS_NEED      ((size_t)RAW_BYTE + RAW_BYTES)

typedef __attribute__((address_space(1))) const void gconst_void;
typedef __attribute__((address_space(3))) void lds_void;
#define GLD_LDS16(gp, lp) __builtin_amdgcn_global_load_lds((gconst_void*)(gp), (lds_void*)(lp), 16, 0, 0)

__device__ __forceinline__ unsigned pack_bf2(float a, float b) {
    unsigned ua = __builtin_bit_cast(unsigned, a) + 0x8000u;
    unsigned ub = __builtin_bit_cast(unsigned, b) + 0x8000u;
    return __builtin_amdgcn_perm(ub, ua, 0x07060302u);
}

__device__ __forceinline__ unsigned short bf16_rne(float f) {
    unsigned u = __builtin_bit_cast(unsigned, f);
    u += 0x7fffu + ((u >> 16) & 1u);
    return (unsigned short)(u >> 16);
}

// ---------------- K1: NCHW fp32 -> padded NHWC bf16 transpose (full-128ch tiles, 256B-line stores)
//                   + ring zeroing + fused repack ----------------
__global__ __launch_bounds__(256) void k_transpose(const float* __restrict__ x, unsigned short* __restrict__ xpad,
                            const float* __restrict__ p_w, short* __restrict__ wofff,
                            const float* __restrict__ w_conv, unsigned short* __restrict__ wrepb,
                            float* __restrict__ stats) {
    __shared__ unsigned tp[64][33];   // bf16-pair packed [c_pair][w], 8.4 KB
    int wt = blockIdx.x, bh = blockIdx.y;
    int w0 = wt * 32;
    int b = bh >> 7, h = bh & 127;
    int t = threadIdx.x;
    int tx = t & 31, ty = t >> 5;     // tx = w_loc, ty = 0..7

    // ---- load + pack: thread handles c-pairs cp = ty + 8i ----
#pragma unroll
    for (int i = 0; i < 8; i++) {
        int cp = ty + 8 * i;
        float a  = x[((size_t)(b * C_ + 2 * cp)     * H_ + h) * W_ + w0 + tx];
        float bb = x[((size_t)(b * C_ + 2 * cp + 1) * H_ + h) * W_ + w0 + tx];
        tp[cp][tx] = pack_bf2(a, bb);
    }

    // ---- fused repack (first 432 flat blocks): p_w->wofff, w_conv->wrepb, stats zero ----
    {
        int fb = bh * 4 + wt;
        int i = fb * 256 + t;
        if (i < 1024) stats[i] = 0.f;
        if (i < 9 * 4096) {
            int e = i & 7, m = (i >> 3) & 31, q = (i >> 8) & 3, kc = (i >> 10) & 3, tap = i >> 12;
            float f = (m < 18) ? p_w[((size_t)m * C_ + kc * 32 + q * 8 + e) * 9 + tap] : 0.f;
            wofff[i] = (short)bf16_rne(f);
        }
        int j = i - 9 * 4096;
        if (j >= 0 && j < 9 * C_ * O_) {
            int ki8 = j & 7;
            int o   = (j >> 3) & 255;
            int kq  = (j >> 11) & 3;
            int kc  = (j >> 13) & 3;
            int n   = j >> 15;
            int c = kc * 32 + kq * 8 + ki8;
            wrepb[j] = bf16_rne(w_conv[(o * C_ + c) * 9 + n]);
        }
    }

    // ---- padding-ring zeroing (full 128-ch, wide stores) ----
    uint4 z4 = make_uint4(0u, 0u, 0u, 0u);
    if (h == 0) {
        // rows hp=0 and hp=129, wp = w0+1..w0+32, all 128 c: 8 threads x 32B per wp
        int wloc = t >> 3, cq = t & 7;
        size_t r0 = ((size_t)(b * HP_ + 0)   * WP_ + (w0 + 1 + wloc)) * C_ + cq * 16;
        size_t r1 = ((size_t)(b * HP_ + 129) * WP_ + (w0 + 1 + wloc)) * C_ + cq * 16;
        *(uint4*)&xpad[r0] = z4; *(uint4*)&xpad[r0 + 8] = z4;
        *(uint4*)&xpad[r1] = z4; *(uint4*)&xpad[r1 + 8] = z4;
        if (wt == 0 && t < 64) {
            // 4 corners x 128 c
            int corner = t >> 4, cq16 = t & 15;
            int hp = (corner & 1) ? 129 : 0;
            int wp = (corner & 2) ? 129 : 0;
            *(uint4*)&xpad[((size_t)(b * HP_ + hp) * WP_ + wp) * C_ + cq16 * 8] = z4;
        }
    }
    if (wt == 0 && t < 32) {
        // cols wp=0 and wp=129 at hp=h+1, all 128 c
        int side = t >> 4, cq16 = t & 15;
        int wp = side ? 129 : 0;
        *(uint4*)&xpad[((size_t)(b * HP_ + h + 1) * WP_ + wp) * C_ + cq16 * 8] = z4;
    }
    __syncthreads();

    // ---- store phase: 8 threads x 32B per wp => 256B full lines, 8KB contiguous per block ----
    {
        int w = t >> 3, cq = t & 7;
        size_t dst = ((size_t)((b * HP_ + h + 1) * WP_ + (w0 + w + 1))) * C_ + cq * 16;
        uint4 v0, v1;
        v0.x = tp[cq * 8 + 0][w]; v0.y = tp[cq * 8 + 1][w];
        v0.z = tp[cq * 8 + 2][w]; v0.w = tp[cq * 8 + 3][w];
        v1.x = tp[cq * 8 + 4][w]; v1.y = tp[cq * 8 + 5][w];
        v1.z = tp[cq * 8 + 6][w]; v1.w = tp[cq * 8 + 7][w];
        *(uint4*)&xpad[dst] = v0;
        *(uint4*)&xpad[dst + 8] = v1;
    }
}

// ---------------- K3: one block per (b,h); fused offset-conv prologue (W prestaged under it) + R1 pipeline ----------------
__global__ __launch_bounds__(512, 4) void k_main(const unsigned short* __restrict__ xpad,
                                                 const short* __restrict__ wofff,
                                                 const float* __restrict__ p_b,
                                                 const unsigned short* __restrict__ wrepb,
                                                 float* __restrict__ out,
                                                 float* __restrict__ stats,
                                                 unsigned short* __restrict__ rawout,
                                                 int bf16flag) {
    __shared__ short Wl[2][8192];        // double-buffered W chunk, 32 KB
    __shared__ short Vl[2][4128];        // double-buffered skewed V, 16.1 KB (off-bounce in prologue, red0/1 after loop)
    __shared__ unsigned pbaseP[9][128];  // packed u8x4 corner coords, 4.5 KB
    __shared__ unsigned pg01[9][128];    // half2(g0,g1), 4.5 KB
    __shared__ unsigned pg23[9][128];    // half2(g2,g3), 4.5 KB

    int t = threadIdx.x;
    int i_blk = blockIdx.x;
    int b = i_blk & 3;
    int h = i_blk >> 2;
    const unsigned short* xb = xpad + (size_t)b * HP_ * WP_ * C_;

    int lane = t & 63, wv = t >> 6;      // 8 waves
    int q = lane >> 4, l15 = lane & 15;
    int m0 = (wv & 3) * 64;              // o-slice
    int ph = wv >> 2;                    // pos half
    int n0 = ph * 64;
    int c4g = t & 3, posb = t >> 2;      // gather: 4 ch-subquads x 128 pos

    // ---- earliest: prestage W[0] AND W[1]; latency hides under the offconv prologue ----
    GLD_LDS16(wrepb + (size_t)t * 8,          &Wl[0][wv * 512]);
    GLD_LDS16(wrepb + (size_t)(t + 512) * 8,  &Wl[0][wv * 512 + 4096]);
    GLD_LDS16(wrepb + 8192 + (size_t)t * 8,         &Wl[1][wv * 512]);
    GLD_LDS16(wrepb + 8192 + (size_t)(t + 512) * 8, &Wl[1][wv * 512 + 4096]);

    // ================= PROLOGUE A: offset conv for this (b,h) =================
    {
        float* off_lds = (float*)&Vl[0][0];          // [18][128] = 9.2 KB bounce, Vl free here
        f32x4 accA = {0.f, 0.f, 0.f, 0.f}, accB = {0.f, 0.f, 0.f, 0.f};
        const bf16x8* Wf = (const bf16x8*)wofff;
        int poscol = wv * 16 + l15;                  // this lane's position 0..127
        for (int tap = 0; tap < 9; tap++) {
            int row = h + tap / 3;
            int col = poscol + tap % 3;
            const unsigned short* src = xb + ((size_t)(row * WP_ + col)) * C_ + q * 8;
#pragma unroll
            for (int kc = 0; kc < 4; kc++) {
                bf16x8 a0 = Wf[(size_t)(((tap * 4 + kc) * 4 + q) * 32) + l15];
                bf16x8 a1 = Wf[(size_t)(((tap * 4 + kc) * 4 + q) * 32) + 16 + l15];
                bf16x8 bv = *(const bf16x8*)(src + kc * 32);
                accA = __builtin_amdgcn_mfma_f32_16x16x32_bf16(a0, bv, accA, 0, 0, 0);
                accB = __builtin_amdgcn_mfma_f32_16x16x32_bf16(a1, bv, accB, 0, 0, 0);
            }
        }
#pragma unroll
        for (int r = 0; r < 4; r++) {
            int j = q * 4 + r;
            off_lds[j * 128 + poscol] = accA[r] + p_b[j];
        }
        if (q == 0) {
#pragma unroll
            for (int r = 0; r < 2; r++) {
                int j = 16 + r;
                off_lds[j * 128 + poscol] = accB[r] + p_b[j];
            }
        }
    }
    __syncthreads();
    // ================= PROLOGUE B: offsets -> packed bilinear tables =================
    if (t < 128) {
        const float* off_lds = (const float*)&Vl[0][0];
        int w = t;
#pragma unroll
        for (int n = 0; n < 9; n++) {
            float offx = off_lds[n * 128 + w];
            float offy = off_lds[(9 + n) * 128 + w];
            float px = (float)(h + n / 3) + offx;        // h+1+(n/3-1)
            float py = (float)(w + n % 3) + offy;        // w+1+(n%3-1)
            float pcx = fminf(fmaxf(px, 0.f), 129.f);
            float pcy = fminf(fmaxf(py, 0.f), 129.f);
            float fx = floorf(px), fy = floorf(py);
            float q0x = fminf(fmaxf(fx, 0.f), 129.f);
            float q0y = fminf(fmaxf(fy, 0.f), 129.f);
            float q1x = fminf(fmaxf(fx + 1.f, 0.f), 129.f);
            float q1y = fminf(fmaxf(fy + 1.f, 0.f), 129.f);
            float wx0 = 1.f + (q0x - pcx), wx1 = 1.f - (q1x - pcx);
            float wy0 = 1.f + (q0y - pcy), wy1 = 1.f - (q1y - pcy);
            unsigned i0x = (unsigned)q0x, i0y = (unsigned)q0y;
            unsigned i1x = (unsigned)q1x, i1y = (unsigned)q1y;
            pbaseP[n][w] = i0x | (i0y << 8) | (i1x << 16) | (i1y << 24);
            __half2 h01 = __floats2half2_rn(wx0 * wy0, wx1 * wy1);
            __half2 h23 = __floats2half2_rn(wx0 * wy1, wx1 * wy0);
            pg01[n][w] = __builtin_bit_cast(unsigned, h01);
            pg23[n][w] = __builtin_bit_cast(unsigned, h23);
        }
    }
    __syncthreads();

    // gather helper: unpack packed tables -> 4 corner bases + 4 weights
    auto UNPACK = [&](int n, int& b0, int& b1, int& b2, int& b3,
                      float& g0, float& g1, float& g2, float& g3) {
        unsigned bp = pbaseP[n][posb];
        int t0 = (int)(bp & 255u) * WP_;
        int y0 = (int)((bp >> 8) & 255u);
        int t1 = (int)((bp >> 16) & 255u) * WP_;
        int y1 = (int)(bp >> 24);
        b0 = (t0 + y0) * C_; b1 = (t1 + y1) * C_;
        b2 = (t0 + y1) * C_; b3 = (t1 + y0) * C_;
        __half2 h01 = __builtin_bit_cast(__half2, pg01[n][posb]);
        __half2 h23 = __builtin_bit_cast(__half2, pg23[n][posb]);
        g0 = __low2float(h01); g1 = __high2float(h01);
        g2 = __low2float(h23); g3 = __high2float(h23);
    };

    f32x4 acc[4][4];
#pragma unroll
    for (int i = 0; i < 4; i++)
#pragma unroll
        for (int j = 0; j < 4; j++) acc[i][j] = (f32x4){0.f, 0.f, 0.f, 0.f};

    // ---- prologue C: gather V for step 0 into Vl[0] (W already staged) ----
    {
        int b0, b1, b2, b3; float g0, g1, g2, g3;
        UNPACK(0, b0, b1, b2, b3, g0, g1, g2, g3);
        int cof = c4g * 8;                           // kc=0
        uint4 A  = *(const uint4*)(xb + b0 + cof);
        uint4 Bv = *(const uint4*)(xb + b1 + cof);
        uint4 Cv = *(const uint4*)(xb + b2 + cof);
        uint4 Dv = *(const uint4*)(xb + b3 + cof);
        unsigned outw[4];
#pragma unroll
        for (int k = 0; k < 4; k++) {
            unsigned ua = (&A.x)[k], ub = (&Bv.x)[k], uc = (&Cv.x)[k], ud = (&Dv.x)[k];
            float alo = __builtin_bit_cast(float, ua << 16), ahi = __builtin_bit_cast(float, ua & 0xffff0000u);
            float blo = __builtin_bit_cast(float, ub << 16), bhi = __builtin_bit_cast(float, ub & 0xffff0000u);
            float clo = __builtin_bit_cast(float, uc << 16), chi = __builtin_bit_cast(float, uc & 0xffff0000u);
            float dlo = __builtin_bit_cast(float, ud << 16), dhi = __builtin_bit_cast(float, ud & 0xffff0000u);
            float vlo = g0 * alo + g1 * blo + g2 * clo + g3 * dlo;
            float vhi = g0 * ahi + g1 * bhi + g2 * chi + g3 * dhi;
            outw[k] = pack_bf2(vlo, vhi);
        }
        *(uint4*)&Vl[0][(unsigned)(c4g * 129 + posb) * 8] = make_uint4(outw[0], outw[1], outw[2], outw[3]);
    }
    __syncthreads();

    // ---- main pipelined loop: 36 steps, 1 barrier per step (R1 proven structure) ----
#pragma unroll 1
    for (int s = 0; s < 36; s++) {
        int cur = s & 1, nxt = cur ^ 1;
        uint4 A, Bv, Cv, Dv;
        float g0 = 0.f, g1 = 0.f, g2 = 0.f, g3 = 0.f;
        bool st = (s < 35);
        if (st) {
            int s1 = s + 1;
            if (s > 0) {   // W[1] was prestaged; stage W[s+1] for s>=1
                const unsigned short* ws = wrepb + (size_t)s1 * 8192;
                GLD_LDS16(ws + (size_t)t * 8, &Wl[nxt][wv * 512]);
                GLD_LDS16(ws + (size_t)(t + 512) * 8, &Wl[nxt][wv * 512 + 4096]);
            }
            int n1 = s1 >> 2, kc1 = s1 & 3;
            int b0, b1, b2, b3;
            UNPACK(n1, b0, b1, b2, b3, g0, g1, g2, g3);
            int cof = kc1 * 32 + c4g * 8;
            A  = *(const uint4*)(xb + b0 + cof);
            Bv = *(const uint4*)(xb + b1 + cof);
            Cv = *(const uint4*)(xb + b2 + cof);
            Dv = *(const uint4*)(xb + b3 + cof);
        }
        // consume step s: loads for s+1 are in flight underneath the MFMAs
        {
            const bf16x8* Af = (const bf16x8*)Wl[cur];
            const bf16x8* Bf = (const bf16x8*)Vl[cur];
            bf16x8 av[4];
#pragma unroll
            for (int i = 0; i < 4; i++) av[i] = Af[q * 256 + m0 + i * 16 + l15];
            __builtin_amdgcn_s_setprio(1);
#pragma unroll
            for (int j = 0; j < 4; j++) {
                bf16x8 bv = Bf[q * 129 + n0 + j * 16 + l15];
#pragma unroll
                for (int i = 0; i < 4; i++)
                    acc[i][j] = __builtin_amdgcn_mfma_f32_16x16x32_bf16(av[i], bv, acc[i][j], 0, 0, 0);
            }
            __builtin_amdgcn_s_setprio(0);
        }
        if (st) {
            unsigned outw[4];
#pragma unroll
            for (int k = 0; k < 4; k++) {
                unsigned ua = (&A.x)[k], ub = (&Bv.x)[k], uc = (&Cv.x)[k], ud = (&Dv.x)[k];
                float alo = __builtin_bit_cast(float, ua << 16), ahi = __builtin_bit_cast(float, ua & 0xffff0000u);
                float blo = __builtin_bit_cast(float, ub << 16), bhi = __builtin_bit_cast(float, ub & 0xffff0000u);
                float clo = __builtin_bit_cast(float, uc << 16), chi = __builtin_bit_cast(float, uc & 0xffff0000u);
                float dlo = __builtin_bit_cast(float, ud << 16), dhi = __builtin_bit_cast(float, ud & 0xffff0000u);
                float vlo = g0 * alo + g1 * blo + g2 * clo + g3 * dlo;
                float vhi = g0 * ahi + g1 * bhi + g2 * chi + g3 * dhi;
                outw[k] = pack_bf2(vlo, vhi);
            }
            *(uint4*)&Vl[nxt][(unsigned)(c4g * 129 + posb) * 8] = make_uint4(outw[0], outw[1], outw[2], outw[3]);
        }
        __syncthreads();
    }

    // ---- epilogue: BN partial sums (red0/red1 aliased onto dead Vl) ----
    float* red0 = (float*)&Vl[0][0];
    float* red1 = red0 + 256;
    if (t < 256) { red0[t] = 0.f; red1[t] = 0.f; }
    __syncthreads();
#pragma unroll
    for (int i = 0; i < 4; i++) {
#pragma unroll
        for (int r = 0; r < 4; r++) {
            int o_loc = m0 + i * 16 + q * 4 + r;
            float s = 0.f, s2 = 0.f;
#pragma unroll
            for (int j = 0; j < 4; j++) { float v = acc[i][j][r]; s += v; s2 += v * v; }
            s  += __shfl_xor(s, 1);  s  += __shfl_xor(s, 2);  s  += __shfl_xor(s, 4);  s  += __shfl_xor(s, 8);
            s2 += __shfl_xor(s2, 1); s2 += __shfl_xor(s2, 2); s2 += __shfl_xor(s2, 4); s2 += __shfl_xor(s2, 8);
            if (l15 == 0) { atomicAdd(&red0[o_loc], s); atomicAdd(&red1[o_loc], s2); }
        }
    }
    __syncthreads();
    if (t < 256) {
        atomicAdd(&stats[t], red0[t]);
        atomicAdd(&stats[256 + t], red1[t]);
    }

    // ---- epilogue: raw C write (bf16 to ws if it fits, else fp32 direct) ----
    if (bf16flag) {
        unsigned short* rb = rawout + ((size_t)b * O_) * HW_ + (size_t)h * W_;
#pragma unroll
        for (int i = 0; i < 4; i++)
#pragma unroll
            for (int j = 0; j < 4; j++) {
                int col = ph * 64 + j * 16 + l15;
#pragma unroll
                for (int r = 0; r < 4; r++) {
                    int o = m0 + i * 16 + q * 4 + r;
                    rb[(size_t)o * HW_ + col] = bf16_rne(acc[i][j][r]);
                }
            }
    } else {
        float* outb = out + ((size_t)b * O_) * HW_ + (size_t)h * W_;
#pragma unroll
        for (int i = 0; i < 4; i++)
#pragma unroll
            for (int j = 0; j < 4; j++) {
                int col = ph * 64 + j * 16 + l15;
#pragma unroll
                for (int r = 0; r < 4; r++) {
                    int o = m0 + i * 16 + q * 4 + r;
                    outb[(size_t)o * HW_ + col] = acc[i][j][r];
                }
            }
    }
}

// ---------------- K5a: BN finalize + normalize + leaky ReLU from bf16 raw ----------------
__global__ __launch_bounds__(256) void k_apply_bf16(const unsigned short* __restrict__ raw,
                                                    float* __restrict__ out,
                                                    const float* __restrict__ stats,
                                                    const float* __restrict__ gamma,
                                                    const float* __restrict__ beta) {
    size_t idx = (size_t)blockIdx.x * 256 + threadIdx.x;
    size_t e = idx * 8;
    int o = (int)((e >> 14) & 255);      // uniform per block
    float s0 = stats[o], s2v = stats[256 + o];
    float mean = s0 * (1.f / 65536.f);
    float var = s2v * (1.f / 65536.f) - mean * mean;
    float sc = gamma[o] * rsqrtf(var + 1e-5f);
    float sh = beta[o] - mean * sc;
    uint4 rv = *(const uint4*)(raw + e);
    float vo[8];
#pragma unroll
    for (int k = 0; k < 4; k++) {
        unsigned w = (&rv.x)[k];
        vo[2 * k]     = __builtin_bit_cast(float, w << 16);
        vo[2 * k + 1] = __builtin_bit_cast(float, w & 0xffff0000u);
    }
#pragma unroll
    for (int k = 0; k < 8; k++) {
        float v = vo[k] * sc + sh;
        vo[k] = (v >= 0.f) ? v : 0.1f * v;
    }
    *(float4*)(out + e)     = make_float4(vo[0], vo[1], vo[2], vo[3]);
    *(float4*)(out + e + 4) = make_float4(vo[4], vo[5], vo[6], vo[7]);
}

// ---------------- K5b: fallback — BN finalize + normalize + leaky ReLU in-place fp32 ----------------
__global__ __launch_bounds__(256) void k_apply_f32(float* __restrict__ out,
                                                   const float* __restrict__ stats,
                                                   const float* __restrict__ gamma,
                                                   const float* __restrict__ beta) {
    int idx = blockIdx.x * 256 + threadIdx.x;
    int e = idx * 4;
    int o = (e >> 14) & 255;
    float s0 = stats[o], s2v = stats[256 + o];
    float mean = s0 * (1.f / 65536.f);
    float var = s2v * (1.f / 65536.f) - mean * mean;
    float sc = gamma[o] * rsqrtf(var + 1e-5f);
    float sh = beta[o] - mean * sc;
    float4 v = *(float4*)(out + e);
    v.x = v.x * sc + sh; v.x = (v.x >= 0.f) ? v.x : 0.1f * v.x;
    v.y = v.y * sc + sh; v.y = (v.y >= 0.f) ? v.y : 0.1f * v.y;
    v.z = v.z * sc + sh; v.z = (v.z >= 0.f) ? v.z : 0.1f * v.z;
    v.w = v.w * sc + sh; v.w = (v.w >= 0.f) ? v.w : 0.1f * v.w;
    *(float4*)(out + e) = v;
}

extern "C" void kernel_launch(void* const* d_in, const int* in_sizes, int n_in,
                              void* d_out, int out_size, void* d_ws, size_t ws_size,
                              hipStream_t stream) {
    const float* x      = (const float*)d_in[0];
    const float* p_w    = (const float*)d_in[1];
    const float* p_b    = (const float*)d_in[2];
    const float* w_conv = (const float*)d_in[3];
    const float* gamma  = (const float*)d_in[4];
    const float* beta   = (const float*)d_in[5];
    float* out = (float*)d_out;

    char* wsb = (char*)d_ws;
    unsigned short* xpad  = (unsigned short*)wsb;
    unsigned short* wrepb = (unsigned short*)(wsb + WREPB_BYTE);
    float*          stats = (float*)(wsb + STATS_BYTE);
    short*          wofff = (short*)(wsb + WOFF_BYTE);
    unsigned short* rawo  = (unsigned short*)(wsb + RAW_BYTE);

    int bf16flag = (ws_size >= WS_NEED) ? 1 : 0;

    k_transpose<<<dim3(4, B_ * H_), 256, 0, stream>>>(
        x, xpad, p_w, wofff, w_conv, wrepb, stats);
    k_main<<<dim3(512), 512, 0, stream>>>(xpad, wofff, p_b, wrepb, out, stats, rawo, bf16flag);
    if (bf16flag)
        k_apply_bf16<<<dim3(B_ * O_ * HW_ / (256 * 8)), 256, 0, stream>>>(rawo, out, stats, gamma, beta);
    else
        k_apply_f32<<<dim3(B_ * O_ * HW_ / (256 * 4)), 256, 0, stream>>>(out, stats, gamma, beta);
}

// Round 10
// 200.910 us; speedup vs baseline: 1.2513x; 1.0484x over previous
//
#include <hip/hip_runtime.h>
#include <hip/hip_fp16.h>
#include <cstdint>

typedef __attribute__((ext_vector_type(8))) _Float16 f16x8;
typedef __attribute__((ext_vector_type(4))) float f32x4;

#define B_   4
#define C_   128
#define H_   128
#define W_   128
#define HP_  130
#define WP_  130
#define O_   256
#define HW_  (H_*W_)          // 16384

// ws layout (byte offsets)
#define XPAD_BYTES   (B_*HP_*WP_*C_*2)          // fp16 xpad: 17,305,600
#define WREPB_BYTE   XPAD_BYTES
#define WREPB_BYTES  (9*C_*O_*2)                // 589,824
#define STATS_BYTE   (WREPB_BYTE + WREPB_BYTES)
#define WOFF_BYTE    (STATS_BYTE + 4096)
#define WOFF_BYTES   (9*4*4*32*8*2)             // 73,728
#define RAW_BYTE     ((WOFF_BYTE + WOFF_BYTES + 255) & ~255)
#define RAW_BYTES    ((size_t)B_*O_*HW_*2)      // 33,554,432 bf16 raw out
#define WS_NEED      ((size_t)RAW_BYTE + RAW_BYTES)

typedef __attribute__((address_space(1))) const void gconst_void;
typedef __attribute__((address_space(3))) void lds_void;
#define GLD_LDS16(gp, lp) __builtin_amdgcn_global_load_lds((gconst_void*)(gp), (lds_void*)(lp), 16, 0, 0)

__device__ __forceinline__ unsigned pack_h2(float a, float b) {
    __half2 h = __floats2half2_rn(a, b);
    return __builtin_bit_cast(unsigned, h);
}

__device__ __forceinline__ unsigned short f16_rn(float f) {
    return __builtin_bit_cast(unsigned short, (_Float16)f);
}

__device__ __forceinline__ unsigned short bf16_rne(float f) {
    unsigned u = __builtin_bit_cast(unsigned, f);
    u += 0x7fffu + ((u >> 16) & 1u);
    return (unsigned short)(u >> 16);
}

// ---------------- K1: NCHW fp32 -> padded NHWC fp16 transpose (full-128ch tiles, 256B-line stores)
//                   + ring zeroing + fused repack ----------------
__global__ __launch_bounds__(256) void k_transpose(const float* __restrict__ x, unsigned short* __restrict__ xpad,
                            const float* __restrict__ p_w, unsigned short* __restrict__ wofff,
                            const float* __restrict__ w_conv, unsigned short* __restrict__ wrepb,
                            float* __restrict__ stats) {
    __shared__ unsigned tp[64][33];   // fp16-pair packed [c_pair][w], 8.4 KB
    int wt = blockIdx.x, bh = blockIdx.y;
    int w0 = wt * 32;
    int b = bh >> 7, h = bh & 127;
    int t = threadIdx.x;
    int tx = t & 31, ty = t >> 5;     // tx = w_loc, ty = 0..7

    // ---- load + pack: thread handles c-pairs cp = ty + 8i ----
#pragma unroll
    for (int i = 0; i < 8; i++) {
        int cp = ty + 8 * i;
        float a  = x[((size_t)(b * C_ + 2 * cp)     * H_ + h) * W_ + w0 + tx];
        float bb = x[((size_t)(b * C_ + 2 * cp + 1) * H_ + h) * W_ + w0 + tx];
        tp[cp][tx] = pack_h2(a, bb);
    }

    // ---- fused repack (first 432 flat blocks): p_w->wofff, w_conv->wrepb, stats zero ----
    {
        int fb = bh * 4 + wt;
        int i = fb * 256 + t;
        if (i < 1024) stats[i] = 0.f;
        if (i < 9 * 4096) {
            int e = i & 7, m = (i >> 3) & 31, q = (i >> 8) & 3, kc = (i >> 10) & 3, tap = i >> 12;
            float f = (m < 18) ? p_w[((size_t)m * C_ + kc * 32 + q * 8 + e) * 9 + tap] : 0.f;
            wofff[i] = f16_rn(f);
        }
        int j = i - 9 * 4096;
        if (j >= 0 && j < 9 * C_ * O_) {
            int ki8 = j & 7;
            int o   = (j >> 3) & 255;
            int kq  = (j >> 11) & 3;
            int kc  = (j >> 13) & 3;
            int n   = j >> 15;
            int c = kc * 32 + kq * 8 + ki8;
            wrepb[j] = f16_rn(w_conv[(o * C_ + c) * 9 + n]);
        }
    }

    // ---- padding-ring zeroing (full 128-ch, wide stores) ----
    uint4 z4 = make_uint4(0u, 0u, 0u, 0u);
    if (h == 0) {
        int wloc = t >> 3, cq = t & 7;
        size_t r0 = ((size_t)(b * HP_ + 0)   * WP_ + (w0 + 1 + wloc)) * C_ + cq * 16;
        size_t r1 = ((size_t)(b * HP_ + 129) * WP_ + (w0 + 1 + wloc)) * C_ + cq * 16;
        *(uint4*)&xpad[r0] = z4; *(uint4*)&xpad[r0 + 8] = z4;
        *(uint4*)&xpad[r1] = z4; *(uint4*)&xpad[r1 + 8] = z4;
        if (wt == 0 && t < 64) {
            int corner = t >> 4, cq16 = t & 15;
            int hp = (corner & 1) ? 129 : 0;
            int wp = (corner & 2) ? 129 : 0;
            *(uint4*)&xpad[((size_t)(b * HP_ + hp) * WP_ + wp) * C_ + cq16 * 8] = z4;
        }
    }
    if (wt == 0 && t < 32) {
        int side = t >> 4, cq16 = t & 15;
        int wp = side ? 129 : 0;
        *(uint4*)&xpad[((size_t)(b * HP_ + h + 1) * WP_ + wp) * C_ + cq16 * 8] = z4;
    }
    __syncthreads();

    // ---- store phase: 8 threads x 32B per wp => 256B full lines ----
    {
        int w = t >> 3, cq = t & 7;
        size_t dst = ((size_t)((b * HP_ + h + 1) * WP_ + (w0 + w + 1))) * C_ + cq * 16;
        uint4 v0, v1;
        v0.x = tp[cq * 8 + 0][w]; v0.y = tp[cq * 8 + 1][w];
        v0.z = tp[cq * 8 + 2][w]; v0.w = tp[cq * 8 + 3][w];
        v1.x = tp[cq * 8 + 4][w]; v1.y = tp[cq * 8 + 5][w];
        v1.z = tp[cq * 8 + 6][w]; v1.w = tp[cq * 8 + 7][w];
        *(uint4*)&xpad[dst] = v0;
        *(uint4*)&xpad[dst + 8] = v1;
    }
}

// ---------------- K3: one block per (b,h); fused offset-conv prologue + R1 pipeline (fp16 V/W) ----------------
__global__ __launch_bounds__(512, 4) void k_main(const unsigned short* __restrict__ xpad,
                                                 const unsigned short* __restrict__ wofff,
                                                 const float* __restrict__ p_b,
                                                 const unsigned short* __restrict__ wrepb,
                                                 float* __restrict__ out,
                                                 float* __restrict__ stats,
                                                 unsigned short* __restrict__ rawout,
                                                 int bf16flag) {
    __shared__ short Wl[2][8192];        // double-buffered W chunk, 32 KB
    __shared__ short Vl[2][4128];        // double-buffered skewed V, 16.1 KB (off-bounce / red0/1 aliased)
    __shared__ unsigned pbaseP[9][128];  // packed u8x4 corner coords, 4.5 KB
    __shared__ unsigned pg01[9][128];    // half2(g0,g1), 4.5 KB
    __shared__ unsigned pg23[9][128];    // half2(g2,g3), 4.5 KB

    int t = threadIdx.x;
    int i_blk = blockIdx.x;
    int b = i_blk & 3;
    int h = i_blk >> 2;
    const unsigned short* xb = xpad + (size_t)b * HP_ * WP_ * C_;

    int lane = t & 63, wv = t >> 6;      // 8 waves
    int q = lane >> 4, l15 = lane & 15;
    int m0 = (wv & 3) * 64;              // o-slice
    int ph = wv >> 2;                    // pos half
    int n0 = ph * 64;
    int c4g = t & 3, posb = t >> 2;      // gather: 4 ch-subquads x 128 pos

    // ---- prestage W[0] AND W[1]; latency hides under the offconv prologue ----
    GLD_LDS16(wrepb + (size_t)t * 8,          &Wl[0][wv * 512]);
    GLD_LDS16(wrepb + (size_t)(t + 512) * 8,  &Wl[0][wv * 512 + 4096]);
    GLD_LDS16(wrepb + 8192 + (size_t)t * 8,         &Wl[1][wv * 512]);
    GLD_LDS16(wrepb + 8192 + (size_t)(t + 512) * 8, &Wl[1][wv * 512 + 4096]);

    // ================= PROLOGUE A: offset conv for this (b,h), fp16 MFMA =================
    {
        float* off_lds = (float*)&Vl[0][0];          // [18][128] bounce, Vl free here
        f32x4 accA = {0.f, 0.f, 0.f, 0.f}, accB = {0.f, 0.f, 0.f, 0.f};
        const f16x8* Wf = (const f16x8*)wofff;
        int poscol = wv * 16 + l15;
        for (int tap = 0; tap < 9; tap++) {
            int row = h + tap / 3;
            int col = poscol + tap % 3;
            const unsigned short* src = xb + ((size_t)(row * WP_ + col)) * C_ + q * 8;
#pragma unroll
            for (int kc = 0; kc < 4; kc++) {
                f16x8 a0 = Wf[(size_t)(((tap * 4 + kc) * 4 + q) * 32) + l15];
                f16x8 a1 = Wf[(size_t)(((tap * 4 + kc) * 4 + q) * 32) + 16 + l15];
                f16x8 bv = *(const f16x8*)(src + kc * 32);
                accA = __builtin_amdgcn_mfma_f32_16x16x32_f16(a0, bv, accA, 0, 0, 0);
                accB = __builtin_amdgcn_mfma_f32_16x16x32_f16(a1, bv, accB, 0, 0, 0);
            }
        }
#pragma unroll
        for (int r = 0; r < 4; r++) {
            int j = q * 4 + r;
            off_lds[j * 128 + poscol] = accA[r] + p_b[j];
        }
        if (q == 0) {
#pragma unroll
            for (int r = 0; r < 2; r++) {
                int j = 16 + r;
                off_lds[j * 128 + poscol] = accB[r] + p_b[j];
            }
        }
    }
    __syncthreads();
    // ================= PROLOGUE B: offsets -> packed bilinear tables =================
    if (t < 128) {
        const float* off_lds = (const float*)&Vl[0][0];
        int w = t;
#pragma unroll
        for (int n = 0; n < 9; n++) {
            float offx = off_lds[n * 128 + w];
            float offy = off_lds[(9 + n) * 128 + w];
            float px = (float)(h + n / 3) + offx;
            float py = (float)(w + n % 3) + offy;
            float pcx = fminf(fmaxf(px, 0.f), 129.f);
            float pcy = fminf(fmaxf(py, 0.f), 129.f);
            float fx = floorf(px), fy = floorf(py);
            float q0x = fminf(fmaxf(fx, 0.f), 129.f);
            float q0y = fminf(fmaxf(fy, 0.f), 129.f);
            float q1x = fminf(fmaxf(fx + 1.f, 0.f), 129.f);
            float q1y = fminf(fmaxf(fy + 1.f, 0.f), 129.f);
            float wx0 = 1.f + (q0x - pcx), wx1 = 1.f - (q1x - pcx);
            float wy0 = 1.f + (q0y - pcy), wy1 = 1.f - (q1y - pcy);
            unsigned i0x = (unsigned)q0x, i0y = (unsigned)q0y;
            unsigned i1x = (unsigned)q1x, i1y = (unsigned)q1y;
            pbaseP[n][w] = i0x | (i0y << 8) | (i1x << 16) | (i1y << 24);
            pg01[n][w] = pack_h2(wx0 * wy0, wx1 * wy1);
            pg23[n][w] = pack_h2(wx0 * wy1, wx1 * wy0);
        }
    }
    __syncthreads();

    // gather helper: unpack packed tables -> 4 corner bases + 4 broadcast half2 weights
    auto UNPACK = [&](int n, int& b0, int& b1, int& b2, int& b3,
                      __half2& g0, __half2& g1, __half2& g2, __half2& g3) {
        unsigned bp = pbaseP[n][posb];
        int t0 = (int)(bp & 255u) * WP_;
        int y0 = (int)((bp >> 8) & 255u);
        int t1 = (int)((bp >> 16) & 255u) * WP_;
        int y1 = (int)(bp >> 24);
        b0 = (t0 + y0) * C_; b1 = (t1 + y1) * C_;
        b2 = (t0 + y1) * C_; b3 = (t1 + y0) * C_;
        __half2 h01 = __builtin_bit_cast(__half2, pg01[n][posb]);
        __half2 h23 = __builtin_bit_cast(__half2, pg23[n][posb]);
        g0 = __half2half2(__low2half(h01)); g1 = __half2half2(__high2half(h01));
        g2 = __half2half2(__low2half(h23)); g3 = __half2half2(__high2half(h23));
    };

    // packed fp16 bilinear blend: 4 ops per 16B-word pair-channel
    auto BLEND4 = [](uint4 A, uint4 Bv, uint4 Cv, uint4 Dv,
                     __half2 g0, __half2 g1, __half2 g2, __half2 g3) -> uint4 {
        unsigned outw[4];
#pragma unroll
        for (int k = 0; k < 4; k++) {
            __half2 a = __builtin_bit_cast(__half2, (&A.x)[k]);
            __half2 bb = __builtin_bit_cast(__half2, (&Bv.x)[k]);
            __half2 c = __builtin_bit_cast(__half2, (&Cv.x)[k]);
            __half2 d = __builtin_bit_cast(__half2, (&Dv.x)[k]);
            __half2 r = __hmul2(g0, a);
            r = __hfma2(g1, bb, r);
            r = __hfma2(g2, c, r);
            r = __hfma2(g3, d, r);
            outw[k] = __builtin_bit_cast(unsigned, r);
        }
        return make_uint4(outw[0], outw[1], outw[2], outw[3]);
    };

    f32x4 acc[4][4];
#pragma unroll
    for (int i = 0; i < 4; i++)
#pragma unroll
        for (int j = 0; j < 4; j++) acc[i][j] = (f32x4){0.f, 0.f, 0.f, 0.f};

    // ---- prologue C: gather V for step 0 into Vl[0] ----
    {
        int b0, b1, b2, b3; __half2 g0, g1, g2, g3;
        UNPACK(0, b0, b1, b2, b3, g0, g1, g2, g3);
        int cof = c4g * 8;
        uint4 A  = *(const uint4*)(xb + b0 + cof);
        uint4 Bv = *(const uint4*)(xb + b1 + cof);
        uint4 Cv = *(const uint4*)(xb + b2 + cof);
        uint4 Dv = *(const uint4*)(xb + b3 + cof);
        *(uint4*)&Vl[0][(unsigned)(c4g * 129 + posb) * 8] = BLEND4(A, Bv, Cv, Dv, g0, g1, g2, g3);
    }
    __syncthreads();

    // ---- main pipelined loop: 36 steps, 1 barrier per step ----
#pragma unroll 1
    for (int s = 0; s < 36; s++) {
        int cur = s & 1, nxt = cur ^ 1;
        uint4 A, Bv, Cv, Dv;
        __half2 g0, g1, g2, g3;
        bool st = (s < 35);
        if (st) {
            int s1 = s + 1;
            if (s > 0) {
                const unsigned short* ws = wrepb + (size_t)s1 * 8192;
                GLD_LDS16(ws + (size_t)t * 8, &Wl[nxt][wv * 512]);
                GLD_LDS16(ws + (size_t)(t + 512) * 8, &Wl[nxt][wv * 512 + 4096]);
            }
            int n1 = s1 >> 2, kc1 = s1 & 3;
            int b0, b1, b2, b3;
            UNPACK(n1, b0, b1, b2, b3, g0, g1, g2, g3);
            int cof = kc1 * 32 + c4g * 8;
            A  = *(const uint4*)(xb + b0 + cof);
            Bv = *(const uint4*)(xb + b1 + cof);
            Cv = *(const uint4*)(xb + b2 + cof);
            Dv = *(const uint4*)(xb + b3 + cof);
        }
        // consume step s
        {
            const f16x8* Af = (const f16x8*)Wl[cur];
            const f16x8* Bf = (const f16x8*)Vl[cur];
            f16x8 av[4];
#pragma unroll
            for (int i = 0; i < 4; i++) av[i] = Af[q * 256 + m0 + i * 16 + l15];
            __builtin_amdgcn_s_setprio(1);
#pragma unroll
            for (int j = 0; j < 4; j++) {
                f16x8 bv = Bf[q * 129 + n0 + j * 16 + l15];
#pragma unroll
                for (int i = 0; i < 4; i++)
                    acc[i][j] = __builtin_amdgcn_mfma_f32_16x16x32_f16(av[i], bv, acc[i][j], 0, 0, 0);
            }
            __builtin_amdgcn_s_setprio(0);
        }
        if (st) {
            *(uint4*)&Vl[nxt][(unsigned)(c4g * 129 + posb) * 8] = BLEND4(A, Bv, Cv, Dv, g0, g1, g2, g3);
        }
        __syncthreads();
    }

    // ---- epilogue: BN partial sums (red0/red1 aliased onto dead Vl) ----
    float* red0 = (float*)&Vl[0][0];
    float* red1 = red0 + 256;
    if (t < 256) { red0[t] = 0.f; red1[t] = 0.f; }
    __syncthreads();
#pragma unroll
    for (int i = 0; i < 4; i++) {
#pragma unroll
        for (int r = 0; r < 4; r++) {
            int o_loc = m0 + i * 16 + q * 4 + r;
            float s = 0.f, s2 = 0.f;
#pragma unroll
            for (int j = 0; j < 4; j++) { float v = acc[i][j][r]; s += v; s2 += v * v; }
            s  += __shfl_xor(s, 1);  s  += __shfl_xor(s, 2);  s  += __shfl_xor(s, 4);  s  += __shfl_xor(s, 8);
            s2 += __shfl_xor(s2, 1); s2 += __shfl_xor(s2, 2); s2 += __shfl_xor(s2, 4); s2 += __shfl_xor(s2, 8);
            if (l15 == 0) { atomicAdd(&red0[o_loc], s); atomicAdd(&red1[o_loc], s2); }
        }
    }
    __syncthreads();
    if (t < 256) {
        atomicAdd(&stats[t], red0[t]);
        atomicAdd(&stats[256 + t], red1[t]);
    }

    // ---- epilogue: raw C write (bf16 to ws if it fits, else fp32 direct) ----
    if (bf16flag) {
        unsigned short* rb = rawout + ((size_t)b * O_) * HW_ + (size_t)h * W_;
#pragma unroll
        for (int i = 0; i < 4; i++)
#pragma unroll
            for (int j = 0; j < 4; j++) {
                int col = ph * 64 + j * 16 + l15;
#pragma unroll
                for (int r = 0; r < 4; r++) {
                    int o = m0 + i * 16 + q * 4 + r;
                    rb[(size_t)o * HW_ + col] = bf16_rne(acc[i][j][r]);
                }
            }
    } else {
        float* outb = out + ((size_t)b * O_) * HW_ + (size_t)h * W_;
#pragma unroll
        for (int i = 0; i < 4; i++)
#pragma unroll
            for (int j = 0; j < 4; j++) {
                int col = ph * 64 + j * 16 + l15;
#pragma unroll
                for (int r = 0; r < 4; r++) {
                    int o = m0 + i * 16 + q * 4 + r;
                    outb[(size_t)o * HW_ + col] = acc[i][j][r];
                }
            }
    }
}

// ---------------- K5a: BN finalize + normalize + leaky ReLU from bf16 raw ----------------
__global__ __launch_bounds__(256) void k_apply_bf16(const unsigned short* __restrict__ raw,
                                                    float* __restrict__ out,
                                                    const float* __restrict__ stats,
                                                    const float* __restrict__ gamma,
                                                    const float* __restrict__ beta) {
    size_t idx = (size_t)blockIdx.x * 256 + threadIdx.x;
    size_t e = idx * 8;
    int o = (int)((e >> 14) & 255);
    float s0 = stats[o], s2v = stats[256 + o];
    float mean = s0 * (1.f / 65536.f);
    float var = s2v * (1.f / 65536.f) - mean * mean;
    float sc = gamma[o] * rsqrtf(var + 1e-5f);
    float sh = beta[o] - mean * sc;
    uint4 rv = *(const uint4*)(raw + e);
    float vo[8];
#pragma unroll
    for (int k = 0; k < 4; k++) {
        unsigned w = (&rv.x)[k];
        vo[2 * k]     = __builtin_bit_cast(float, w << 16);
        vo[2 * k + 1] = __builtin_bit_cast(float, w & 0xffff0000u);
    }
#pragma unroll
    for (int k = 0; k < 8; k++) {
        float v = vo[k] * sc + sh;
        vo[k] = (v >= 0.f) ? v : 0.1f * v;
    }
    *(float4*)(out + e)     = make_float4(vo[0], vo[1], vo[2], vo[3]);
    *(float4*)(out + e + 4) = make_float4(vo[4], vo[5], vo[6], vo[7]);
}

// ---------------- K5b: fallback — BN finalize + normalize + leaky ReLU in-place fp32 ----------------
__global__ __launch_bounds__(256) void k_apply_f32(float* __restrict__ out,
                                                   const float* __restrict__ stats,
                                                   const float* __restrict__ gamma,
                                                   const float* __restrict__ beta) {
    int idx = blockIdx.x * 256 + threadIdx.x;
    int e = idx * 4;
    int o = (e >> 14) & 255;
    float s0 = stats[o], s2v = stats[256 + o];
    float mean = s0 * (1.f / 65536.f);
    float var = s2v * (1.f / 65536.f) - mean * mean;
    float sc = gamma[o] * rsqrtf(var + 1e-5f);
    float sh = beta[o] - mean * sc;
    float4 v = *(float4*)(out + e);
    v.x = v.x * sc + sh; v.x = (v.x >= 0.f) ? v.x : 0.1f * v.x;
    v.y = v.y * sc + sh; v.y = (v.y >= 0.f) ? v.y : 0.1f * v.y;
    v.z = v.z * sc + sh; v.z = (v.z >= 0.f) ? v.z : 0.1f * v.z;
    v.w = v.w * sc + sh; v.w = (v.w >= 0.f) ? v.w : 0.1f * v.w;
    *(float4*)(out + e) = v;
}

extern "C" void kernel_launch(void* const* d_in, const int* in_sizes, int n_in,
                              void* d_out, int out_size, void* d_ws, size_t ws_size,
                              hipStream_t stream) {
    const float* x      = (const float*)d_in[0];
    const float* p_w    = (const float*)d_in[1];
    const float* p_b    = (const float*)d_in[2];
    const float* w_conv = (const float*)d_in[3];
    const float* gamma  = (const float*)d_in[4];
    const float* beta   = (const float*)d_in[5];
    float* out = (float*)d_out;

    char* wsb = (char*)d_ws;
    unsigned short* xpad  = (unsigned short*)wsb;
    unsigned short* wrepb = (unsigned short*)(wsb + WREPB_BYTE);
    float*          stats = (float*)(wsb + STATS_BYTE);
    unsigned short* wofff = (unsigned short*)(wsb + WOFF_BYTE);
    unsigned short* rawo  = (unsigned short*)(wsb + RAW_BYTE);

    int bf16flag = (ws_size >= WS_NEED) ? 1 : 0;

    k_transpose<<<dim3(4, B_ * H_), 256, 0, stream>>>(
        x, xpad, p_w, wofff, w_conv, wrepb, stats);
    k_main<<<dim3(512), 512, 0, stream>>>(xpad, wofff, p_b, wrepb, out, stats, rawo, bf16flag);
    if (bf16flag)
        k_apply_bf16<<<dim3(B_ * O_ * HW_ / (256 * 8)), 256, 0, stream>>>(rawo, out, stats, gamma, beta);
    else
        k_apply_f32<<<dim3(B_ * O_ * HW_ / (256 * 4)), 256, 0, stream>>>(out, stats, gamma, beta);
}